// Round 2
// baseline (27995.471 us; speedup 1.0000x reference)
//
#include <hip/hip_runtime.h>
#include <hip/hip_bf16.h>

#define VSZ 128
#define EMBD 64
#define HSZ 512
#define BSZ 256
#define TLEN 512

typedef __attribute__((ext_vector_type(8))) short short8;
typedef __attribute__((ext_vector_type(4))) float f32x4;
typedef __hip_bfloat16 bf16;

// ---- workspace layout (bf16 element offsets) ----
#define O_WHH0HI ((size_t)0)
#define O_WHH0LO (O_WHH0HI + (size_t)HSZ*HSZ)
#define O_WIH1HI (O_WHH0LO + (size_t)HSZ*HSZ)
#define O_WIH1LO (O_WIH1HI + (size_t)HSZ*HSZ)
#define O_WHH1HI (O_WIH1LO + (size_t)HSZ*HSZ)
#define O_WHH1LO (O_WHH1HI + (size_t)HSZ*HSZ)
#define O_WIH0HI (O_WHH1LO + (size_t)HSZ*HSZ)     // [N=512][K=64]
#define O_WIH0LO (O_WIH0HI + (size_t)HSZ*EMBD)
#define O_WFCHI  (O_WIH0LO + (size_t)HSZ*EMBD)    // [N=128][K=512]
#define O_WFCLO  (O_WFCHI + (size_t)VSZ*HSZ)
#define O_EMBHI  (O_WFCLO + (size_t)VSZ*HSZ)      // [128][64] row-major
#define O_EMBLO  (O_EMBHI + (size_t)VSZ*EMBD)
#define O_H0HI   (O_EMBLO + (size_t)VSZ*EMBD)     // [2][256][512] ping-pong
#define O_H0LO   (O_H0HI + (size_t)2*BSZ*HSZ)
#define O_H1HI   (O_H0LO + (size_t)2*BSZ*HSZ)
#define O_H1LO   (O_H1HI + (size_t)2*BSZ*HSZ)

static __device__ __forceinline__ short8 ld8(const bf16* p) {
    return *(const short8*)p;
}
static __device__ __forceinline__ float b2f(bf16 v) { return __bfloat162float(v); }

#define MFMA(a,b,c) __builtin_amdgcn_mfma_f32_16x16x32_bf16((a),(b),(c),0,0,0)

// fp32 [K][N] row-major -> transposed bf16 hi/lo [N][K]
__global__ void k_splitT(const float* __restrict__ in, bf16* __restrict__ outhi,
                         bf16* __restrict__ outlo, int K, int N) {
    int i = blockIdx.x * blockDim.x + threadIdx.x;
    if (i >= K * N) return;
    int n = i / K;
    int k = i - n * K;
    float w = in[k * N + n];
    bf16 hi = __float2bfloat16(w);
    outhi[i] = hi;
    outlo[i] = __float2bfloat16(w - b2f(hi));
}

// fp32 -> bf16 hi/lo, same layout
__global__ void k_split_row(const float* __restrict__ in, bf16* __restrict__ outhi,
                            bf16* __restrict__ outlo, int total) {
    int i = blockIdx.x * blockDim.x + threadIdx.x;
    if (i >= total) return;
    float w = in[i];
    bf16 hi = __float2bfloat16(w);
    outhi[i] = hi;
    outlo[i] = __float2bfloat16(w - b2f(hi));
}

__global__ void k_zero(unsigned int* __restrict__ p, int n32) {
    int i = blockIdx.x * blockDim.x + threadIdx.x;
    if (i < n32) p[i] = 0u;
}

// ---- layer 0 step: h0_t = tanh(emb[x[:,t]] @ Wih0 + h0_{t-1} @ Whh0 + b) ----
// grid 32 blocks x 256 threads; block tile 64x64, wave tile 32x32 (2x2 of 16x16)
__global__ __launch_bounds__(256) void k_step0(
    const int* __restrict__ x,
    const bf16* __restrict__ embhi, const bf16* __restrict__ emblo,
    const bf16* __restrict__ Wih0hi, const bf16* __restrict__ Wih0lo,
    const bf16* __restrict__ Whh0hi, const bf16* __restrict__ Whh0lo,
    const float* __restrict__ bih0, const float* __restrict__ bhh0,
    bf16* __restrict__ h0hi, bf16* __restrict__ h0lo, int t)
{
    const int lane = threadIdx.x & 63;
    const int wv   = threadIdx.x >> 6;
    const int l15  = lane & 15;
    const int quad = lane >> 4;
    const int rs = t & 1, wsl = rs ^ 1;

    const int mblk = ((int)blockIdx.x >> 3) * 64 + (wv >> 1) * 32;
    const int nblk = ((int)blockIdx.x & 7) * 64 + (wv & 1) * 32;

    const bf16* hp_hi = h0hi + (size_t)rs * (BSZ * HSZ);
    const bf16* hp_lo = h0lo + (size_t)rs * (BSZ * HSZ);
    bf16* hc_hi = h0hi + (size_t)wsl * (BSZ * HSZ);
    bf16* hc_lo = h0lo + (size_t)wsl * (BSZ * HSZ);

    f32x4 acc[2][2] = {};

    const int row0 = mblk + l15;
    const int row1 = mblk + 16 + l15;

    // embedding-gather GEMM, K = 64, 3-term hi/lo
    const int x0 = x[row0 * TLEN + t];
    const int x1 = x[row1 * TLEN + t];
#pragma unroll
    for (int kc = 0; kc < EMBD; kc += 32) {
        short8 ah0 = ld8(embhi + (size_t)x0 * EMBD + kc + quad * 8);
        short8 ah1 = ld8(embhi + (size_t)x1 * EMBD + kc + quad * 8);
        short8 al0 = ld8(emblo + (size_t)x0 * EMBD + kc + quad * 8);
        short8 al1 = ld8(emblo + (size_t)x1 * EMBD + kc + quad * 8);
#pragma unroll
        for (int ni = 0; ni < 2; ni++) {
            int n = nblk + ni * 16 + l15;
            short8 bh = ld8(Wih0hi + (size_t)n * EMBD + kc + quad * 8);
            short8 bl = ld8(Wih0lo + (size_t)n * EMBD + kc + quad * 8);
            acc[0][ni] = MFMA(ah0, bh, acc[0][ni]);
            acc[0][ni] = MFMA(al0, bh, acc[0][ni]);
            acc[0][ni] = MFMA(ah0, bl, acc[0][ni]);
            acc[1][ni] = MFMA(ah1, bh, acc[1][ni]);
            acc[1][ni] = MFMA(al1, bh, acc[1][ni]);
            acc[1][ni] = MFMA(ah1, bl, acc[1][ni]);
        }
    }

    // hh GEMM, K = 512, 3-term hi/lo
    for (int kc = 0; kc < HSZ; kc += 32) {
        short8 ah0 = ld8(hp_hi + (size_t)row0 * HSZ + kc + quad * 8);
        short8 ah1 = ld8(hp_hi + (size_t)row1 * HSZ + kc + quad * 8);
        short8 al0 = ld8(hp_lo + (size_t)row0 * HSZ + kc + quad * 8);
        short8 al1 = ld8(hp_lo + (size_t)row1 * HSZ + kc + quad * 8);
#pragma unroll
        for (int ni = 0; ni < 2; ni++) {
            int n = nblk + ni * 16 + l15;
            short8 bh = ld8(Whh0hi + (size_t)n * HSZ + kc + quad * 8);
            short8 bl = ld8(Whh0lo + (size_t)n * HSZ + kc + quad * 8);
            acc[0][ni] = MFMA(ah0, bh, acc[0][ni]);
            acc[0][ni] = MFMA(al0, bh, acc[0][ni]);
            acc[0][ni] = MFMA(ah0, bl, acc[0][ni]);
            acc[1][ni] = MFMA(ah1, bh, acc[1][ni]);
            acc[1][ni] = MFMA(al1, bh, acc[1][ni]);
            acc[1][ni] = MFMA(ah1, bl, acc[1][ni]);
        }
    }

    // epilogue: bias + tanh, write hi/lo
#pragma unroll
    for (int mi = 0; mi < 2; mi++) {
#pragma unroll
        for (int ni = 0; ni < 2; ni++) {
            int col = nblk + ni * 16 + l15;
            float bias = bih0[col] + bhh0[col];
#pragma unroll
            for (int r = 0; r < 4; r++) {
                int row = mblk + mi * 16 + quad * 4 + r;
                float v = tanhf(acc[mi][ni][r] + bias);
                bf16 hi = __float2bfloat16(v);
                float rem = v - b2f(hi);
                hc_hi[(size_t)row * HSZ + col] = hi;
                hc_lo[(size_t)row * HSZ + col] = __float2bfloat16(rem);
            }
        }
    }
}

// FC tile: logits[:, tout, :] = h1 @ Wfc + b_fc  (h1 given as hi/lo slabs)
static __device__ __forceinline__ void fc_block(
    const bf16* __restrict__ hhi, const bf16* __restrict__ hlo,
    const bf16* __restrict__ Wfchi, const bf16* __restrict__ Wfclo,
    const float* __restrict__ bfc,
    float* __restrict__ out, int fb, int wv, int lane, int tout)
{
    const int l15 = lane & 15, quad = lane >> 4;
    const int mblk = (fb >> 1) * 64 + (wv >> 1) * 32;
    const int nblk = (fb & 1) * 64 + (wv & 1) * 32;
    const int row0 = mblk + l15, row1 = mblk + 16 + l15;

    f32x4 acc[2][2] = {};
    for (int kc = 0; kc < HSZ; kc += 32) {
        short8 ah0 = ld8(hhi + (size_t)row0 * HSZ + kc + quad * 8);
        short8 ah1 = ld8(hhi + (size_t)row1 * HSZ + kc + quad * 8);
        short8 al0 = ld8(hlo + (size_t)row0 * HSZ + kc + quad * 8);
        short8 al1 = ld8(hlo + (size_t)row1 * HSZ + kc + quad * 8);
#pragma unroll
        for (int ni = 0; ni < 2; ni++) {
            int n = nblk + ni * 16 + l15;
            short8 bh = ld8(Wfchi + (size_t)n * HSZ + kc + quad * 8);
            short8 bl = ld8(Wfclo + (size_t)n * HSZ + kc + quad * 8);
            acc[0][ni] = MFMA(ah0, bh, acc[0][ni]);
            acc[0][ni] = MFMA(al0, bh, acc[0][ni]);
            acc[0][ni] = MFMA(ah0, bl, acc[0][ni]);
            acc[1][ni] = MFMA(ah1, bh, acc[1][ni]);
            acc[1][ni] = MFMA(al1, bh, acc[1][ni]);
            acc[1][ni] = MFMA(ah1, bl, acc[1][ni]);
        }
    }
#pragma unroll
    for (int mi = 0; mi < 2; mi++) {
#pragma unroll
        for (int ni = 0; ni < 2; ni++) {
            int col = nblk + ni * 16 + l15;
            float bias = bfc[col];
#pragma unroll
            for (int r = 0; r < 4; r++) {
                int row = mblk + mi * 16 + quad * 4 + r;
                out[((size_t)row * TLEN + tout) * VSZ + col] = acc[mi][ni][r] + bias;
            }
        }
    }
}

// ---- layer 1 step (+ pipelined FC of step t-1 on blocks 32..39) ----
__global__ __launch_bounds__(256) void k_step1(
    const bf16* __restrict__ Wih1hi, const bf16* __restrict__ Wih1lo,
    const bf16* __restrict__ Whh1hi, const bf16* __restrict__ Whh1lo,
    const float* __restrict__ bih1, const float* __restrict__ bhh1,
    const bf16* __restrict__ Wfchi, const bf16* __restrict__ Wfclo,
    const float* __restrict__ bfc,
    const bf16* __restrict__ h0hi, const bf16* __restrict__ h0lo,
    bf16* __restrict__ h1hi, bf16* __restrict__ h1lo,
    float* __restrict__ out, int t)
{
    const int lane = threadIdx.x & 63;
    const int wv   = threadIdx.x >> 6;
    const int rs = t & 1, wsl = rs ^ 1;

    if (blockIdx.x >= 32) {
        if (t == 0) return;
        fc_block(h1hi + (size_t)rs * (BSZ * HSZ), h1lo + (size_t)rs * (BSZ * HSZ),
                 Wfchi, Wfclo, bfc, out, (int)blockIdx.x - 32, wv, lane, t - 1);
        return;
    }

    const int l15 = lane & 15, quad = lane >> 4;
    const int mblk = ((int)blockIdx.x >> 3) * 64 + (wv >> 1) * 32;
    const int nblk = ((int)blockIdx.x & 7) * 64 + (wv & 1) * 32;

    const bf16* a0hi = h0hi + (size_t)wsl * (BSZ * HSZ);  // h0_t (just written)
    const bf16* a0lo = h0lo + (size_t)wsl * (BSZ * HSZ);
    const bf16* a1hi = h1hi + (size_t)rs * (BSZ * HSZ);   // h1_{t-1}
    const bf16* a1lo = h1lo + (size_t)rs * (BSZ * HSZ);
    bf16* hc_hi = h1hi + (size_t)wsl * (BSZ * HSZ);
    bf16* hc_lo = h1lo + (size_t)wsl * (BSZ * HSZ);

    const int row0 = mblk + l15, row1 = mblk + 16 + l15;
    f32x4 acc[2][2] = {};

    for (int kc = 0; kc < HSZ; kc += 32) {
        short8 p0 = ld8(a0hi + (size_t)row0 * HSZ + kc + quad * 8);
        short8 p1 = ld8(a0hi + (size_t)row1 * HSZ + kc + quad * 8);
        short8 q0 = ld8(a0lo + (size_t)row0 * HSZ + kc + quad * 8);
        short8 q1 = ld8(a0lo + (size_t)row1 * HSZ + kc + quad * 8);
        short8 r0 = ld8(a1hi + (size_t)row0 * HSZ + kc + quad * 8);
        short8 r1 = ld8(a1hi + (size_t)row1 * HSZ + kc + quad * 8);
        short8 s0 = ld8(a1lo + (size_t)row0 * HSZ + kc + quad * 8);
        short8 s1 = ld8(a1lo + (size_t)row1 * HSZ + kc + quad * 8);
#pragma unroll
        for (int ni = 0; ni < 2; ni++) {
            int n = nblk + ni * 16 + l15;
            short8 bih = ld8(Wih1hi + (size_t)n * HSZ + kc + quad * 8);
            short8 bil = ld8(Wih1lo + (size_t)n * HSZ + kc + quad * 8);
            short8 bhh = ld8(Whh1hi + (size_t)n * HSZ + kc + quad * 8);
            short8 bhl = ld8(Whh1lo + (size_t)n * HSZ + kc + quad * 8);
            acc[0][ni] = MFMA(p0, bih, acc[0][ni]);
            acc[0][ni] = MFMA(q0, bih, acc[0][ni]);
            acc[0][ni] = MFMA(p0, bil, acc[0][ni]);
            acc[0][ni] = MFMA(r0, bhh, acc[0][ni]);
            acc[0][ni] = MFMA(s0, bhh, acc[0][ni]);
            acc[0][ni] = MFMA(r0, bhl, acc[0][ni]);
            acc[1][ni] = MFMA(p1, bih, acc[1][ni]);
            acc[1][ni] = MFMA(q1, bih, acc[1][ni]);
            acc[1][ni] = MFMA(p1, bil, acc[1][ni]);
            acc[1][ni] = MFMA(r1, bhh, acc[1][ni]);
            acc[1][ni] = MFMA(s1, bhh, acc[1][ni]);
            acc[1][ni] = MFMA(r1, bhl, acc[1][ni]);
        }
    }

#pragma unroll
    for (int mi = 0; mi < 2; mi++) {
#pragma unroll
        for (int ni = 0; ni < 2; ni++) {
            int col = nblk + ni * 16 + l15;
            float bias = bih1[col] + bhh1[col];
#pragma unroll
            for (int r = 0; r < 4; r++) {
                int row = mblk + mi * 16 + quad * 4 + r;
                float v = tanhf(acc[mi][ni][r] + bias);
                bf16 hi = __float2bfloat16(v);
                float rem = v - b2f(hi);
                hc_hi[(size_t)row * HSZ + col] = hi;
                hc_lo[(size_t)row * HSZ + col] = __float2bfloat16(rem);
            }
        }
    }
}

// final FC for t = TLEN-1 (step 511 wrote slot (511&1)^1 = 0)
__global__ __launch_bounds__(256) void k_fc_last(
    const bf16* __restrict__ h1hi, const bf16* __restrict__ h1lo,
    const bf16* __restrict__ Wfchi, const bf16* __restrict__ Wfclo,
    const float* __restrict__ bfc, float* __restrict__ out)
{
    const int lane = threadIdx.x & 63;
    const int wv = threadIdx.x >> 6;
    fc_block(h1hi, h1lo, Wfchi, Wfclo, bfc, out, (int)blockIdx.x, wv, lane, TLEN - 1);
}

extern "C" void kernel_launch(void* const* d_in, const int* in_sizes, int n_in,
                              void* d_out, int out_size, void* d_ws, size_t ws_size,
                              hipStream_t stream) {
    const int*   x    = (const int*)d_in[0];
    const float* emb  = (const float*)d_in[1];
    const float* Wih0 = (const float*)d_in[2];
    const float* bih0 = (const float*)d_in[3];
    const float* Whh0 = (const float*)d_in[4];
    const float* bhh0 = (const float*)d_in[5];
    const float* Wih1 = (const float*)d_in[6];
    const float* bih1 = (const float*)d_in[7];
    const float* Whh1 = (const float*)d_in[8];
    const float* bhh1 = (const float*)d_in[9];
    const float* Wfc  = (const float*)d_in[10];
    const float* bfc  = (const float*)d_in[11];
    float* out = (float*)d_out;
    bf16* ws   = (bf16*)d_ws;

    bf16* Whh0hi = ws + O_WHH0HI; bf16* Whh0lo = ws + O_WHH0LO;
    bf16* Wih1hi = ws + O_WIH1HI; bf16* Wih1lo = ws + O_WIH1LO;
    bf16* Whh1hi = ws + O_WHH1HI; bf16* Whh1lo = ws + O_WHH1LO;
    bf16* Wih0hi = ws + O_WIH0HI; bf16* Wih0lo = ws + O_WIH0LO;
    bf16* Wfchi  = ws + O_WFCHI;  bf16* Wfclo  = ws + O_WFCLO;
    bf16* embhi  = ws + O_EMBHI;  bf16* emblo  = ws + O_EMBLO;
    bf16* h0hi   = ws + O_H0HI;   bf16* h0lo   = ws + O_H0LO;
    bf16* h1hi   = ws + O_H1HI;   bf16* h1lo   = ws + O_H1LO;

    // prep: split+transpose weights to bf16 hi/lo, zero hidden ping-pong slabs
    {
        int tot = HSZ * HSZ;
        k_splitT<<<(tot + 255) / 256, 256, 0, stream>>>(Whh0, Whh0hi, Whh0lo, HSZ, HSZ);
        k_splitT<<<(tot + 255) / 256, 256, 0, stream>>>(Wih1, Wih1hi, Wih1lo, HSZ, HSZ);
        k_splitT<<<(tot + 255) / 256, 256, 0, stream>>>(Whh1, Whh1hi, Whh1lo, HSZ, HSZ);
        int t2 = EMBD * HSZ;
        k_splitT<<<(t2 + 255) / 256, 256, 0, stream>>>(Wih0, Wih0hi, Wih0lo, EMBD, HSZ);
        int t3 = HSZ * VSZ;
        k_splitT<<<(t3 + 255) / 256, 256, 0, stream>>>(Wfc, Wfchi, Wfclo, HSZ, VSZ);
        int t4 = VSZ * EMBD;
        k_split_row<<<(t4 + 255) / 256, 256, 0, stream>>>(emb, embhi, emblo, t4);
        int n32 = (int)((size_t)8 * BSZ * HSZ * sizeof(bf16) / 4);
        k_zero<<<(n32 + 255) / 256, 256, 0, stream>>>((unsigned int*)(ws + O_H0HI), n32);
    }

    for (int t = 0; t < TLEN; t++) {
        k_step0<<<32, 256, 0, stream>>>(x, embhi, emblo, Wih0hi, Wih0lo,
                                        Whh0hi, Whh0lo, bih0, bhh0, h0hi, h0lo, t);
        k_step1<<<40, 256, 0, stream>>>(Wih1hi, Wih1lo, Whh1hi, Whh1lo, bih1, bhh1,
                                        Wfchi, Wfclo, bfc, h0hi, h0lo, h1hi, h1lo, out, t);
    }
    k_fc_last<<<8, 256, 0, stream>>>(h1hi, h1lo, Wfchi, Wfclo, bfc, out);
}

// Round 3
// 20568.880 us; speedup vs baseline: 1.3611x; 1.3611x over previous
//
#include <hip/hip_runtime.h>
#include <hip/hip_bf16.h>

#define VSZ 128
#define EMBD 64
#define HSZ 512
#define BSZ 256
#define TLEN 512
#define NBLK 72   // 32 layer0 + 32 layer1 + 8 fc

typedef __attribute__((ext_vector_type(8))) short short8;
typedef __attribute__((ext_vector_type(4))) float f32x4;
typedef __hip_bfloat16 bf16;

// ---- workspace layout (bf16 element offsets) ----
#define O_WHH0HI ((size_t)0)
#define O_WHH0LO (O_WHH0HI + (size_t)HSZ*HSZ)
#define O_WIH1HI (O_WHH0LO + (size_t)HSZ*HSZ)
#define O_WIH1LO (O_WIH1HI + (size_t)HSZ*HSZ)
#define O_WHH1HI (O_WIH1LO + (size_t)HSZ*HSZ)
#define O_WHH1LO (O_WHH1HI + (size_t)HSZ*HSZ)
#define O_WIH0HI (O_WHH1LO + (size_t)HSZ*HSZ)     // [N=512][K=64]
#define O_WIH0LO (O_WIH0HI + (size_t)HSZ*EMBD)
#define O_WFCHI  (O_WIH0LO + (size_t)HSZ*EMBD)    // [N=128][K=512]
#define O_WFCLO  (O_WFCHI + (size_t)VSZ*HSZ)
#define O_EMBHI  (O_WFCLO + (size_t)VSZ*HSZ)      // [128][64] row-major
#define O_EMBLO  (O_EMBHI + (size_t)VSZ*EMBD)
#define O_H0HI   (O_EMBLO + (size_t)VSZ*EMBD)     // [2][256][512] ping-pong
#define O_H0LO   (O_H0HI + (size_t)2*BSZ*HSZ)
#define O_H1HI   (O_H0LO + (size_t)2*BSZ*HSZ)
#define O_H1LO   (O_H1HI + (size_t)2*BSZ*HSZ)
#define O_BAR    (O_H1LO + (size_t)2*BSZ*HSZ)     // barrier counter (u32) + pad

static __device__ __forceinline__ short8 ld8(const bf16* p) {
    return *(const short8*)p;
}
static __device__ __forceinline__ float b2f(bf16 v) { return __bfloat162float(v); }

#define MFMA(a,b,c) __builtin_amdgcn_mfma_f32_16x16x32_bf16((a),(b),(c),0,0,0)

// ---- one prep kernel: split/transpose all weights to bf16 hi/lo + zero state ----
__global__ void k_prep(const float* __restrict__ emb, const float* __restrict__ Wih0,
                       const float* __restrict__ Whh0, const float* __restrict__ Wih1,
                       const float* __restrict__ Whh1, const float* __restrict__ Wfc,
                       bf16* __restrict__ ws) {
    int j = blockIdx.x * blockDim.x + threadIdx.x;
    const int SQ = HSZ * HSZ;              // 262144
    // Whh0T
    if (j < SQ) {
        int n = j / HSZ, k = j - n * HSZ;
        float w = Whh0[k * HSZ + n];
        bf16 hi = __float2bfloat16(w);
        ws[O_WHH0HI + j] = hi; ws[O_WHH0LO + j] = __float2bfloat16(w - b2f(hi));
        return;
    }
    j -= SQ;
    if (j < SQ) {  // Wih1T
        int n = j / HSZ, k = j - n * HSZ;
        float w = Wih1[k * HSZ + n];
        bf16 hi = __float2bfloat16(w);
        ws[O_WIH1HI + j] = hi; ws[O_WIH1LO + j] = __float2bfloat16(w - b2f(hi));
        return;
    }
    j -= SQ;
    if (j < SQ) {  // Whh1T
        int n = j / HSZ, k = j - n * HSZ;
        float w = Whh1[k * HSZ + n];
        bf16 hi = __float2bfloat16(w);
        ws[O_WHH1HI + j] = hi; ws[O_WHH1LO + j] = __float2bfloat16(w - b2f(hi));
        return;
    }
    j -= SQ;
    if (j < HSZ * EMBD) {  // Wih0T: out [512][64], in [64][512]
        int n = j / EMBD, k = j - n * EMBD;
        float w = Wih0[k * HSZ + n];
        bf16 hi = __float2bfloat16(w);
        ws[O_WIH0HI + j] = hi; ws[O_WIH0LO + j] = __float2bfloat16(w - b2f(hi));
        return;
    }
    j -= HSZ * EMBD;
    if (j < VSZ * HSZ) {   // WfcT: out [128][512], in [512][128]
        int n = j / HSZ, k = j - n * HSZ;
        float w = Wfc[k * VSZ + n];
        bf16 hi = __float2bfloat16(w);
        ws[O_WFCHI + j] = hi; ws[O_WFCLO + j] = __float2bfloat16(w - b2f(hi));
        return;
    }
    j -= VSZ * HSZ;
    if (j < VSZ * EMBD) {  // emb split (no transpose)
        float w = emb[j];
        bf16 hi = __float2bfloat16(w);
        ws[O_EMBHI + j] = hi; ws[O_EMBLO + j] = __float2bfloat16(w - b2f(hi));
        return;
    }
    j -= VSZ * EMBD;
    // zero: h slabs (8*BSZ*HSZ bf16 = 524288 u32) + barrier line (64 u32)
    const int NZ = (8 * BSZ * HSZ) / 2 + 64;
    if (j < NZ) {
        ((unsigned int*)(ws + O_H0HI))[j] = 0u;
    }
}

// ---- layer 0 tile: h0_t = tanh(emb[x[:,t]] @ Wih0 + h0_{t-1} @ Whh0 + b) ----
static __device__ __forceinline__ void step0_tile(
    int t, int fb, int wv, int lane,
    const int* __restrict__ x,
    const bf16* __restrict__ embhi, const bf16* __restrict__ emblo,
    const bf16* __restrict__ Wih0hi, const bf16* __restrict__ Wih0lo,
    const bf16* __restrict__ Whh0hi, const bf16* __restrict__ Whh0lo,
    const float* __restrict__ bih0, const float* __restrict__ bhh0,
    bf16* __restrict__ h0hi, bf16* __restrict__ h0lo)
{
    const int l15 = lane & 15, quad = lane >> 4;
    const int rs = t & 1, wsl = rs ^ 1;
    const int mblk = (fb >> 3) * 64 + (wv >> 1) * 32;
    const int nblk = (fb & 7) * 64 + (wv & 1) * 32;

    const bf16* hp_hi = h0hi + (size_t)rs * (BSZ * HSZ);
    const bf16* hp_lo = h0lo + (size_t)rs * (BSZ * HSZ);
    bf16* hc_hi = h0hi + (size_t)wsl * (BSZ * HSZ);
    bf16* hc_lo = h0lo + (size_t)wsl * (BSZ * HSZ);

    f32x4 acc[2][2] = {};
    const int row0 = mblk + l15, row1 = mblk + 16 + l15;

    const int x0 = x[row0 * TLEN + t];
    const int x1 = x[row1 * TLEN + t];
#pragma unroll
    for (int kc = 0; kc < EMBD; kc += 32) {
        short8 ah0 = ld8(embhi + (size_t)x0 * EMBD + kc + quad * 8);
        short8 ah1 = ld8(embhi + (size_t)x1 * EMBD + kc + quad * 8);
        short8 al0 = ld8(emblo + (size_t)x0 * EMBD + kc + quad * 8);
        short8 al1 = ld8(emblo + (size_t)x1 * EMBD + kc + quad * 8);
#pragma unroll
        for (int ni = 0; ni < 2; ni++) {
            int n = nblk + ni * 16 + l15;
            short8 bh = ld8(Wih0hi + (size_t)n * EMBD + kc + quad * 8);
            short8 bl = ld8(Wih0lo + (size_t)n * EMBD + kc + quad * 8);
            acc[0][ni] = MFMA(ah0, bh, acc[0][ni]);
            acc[0][ni] = MFMA(al0, bh, acc[0][ni]);
            acc[0][ni] = MFMA(ah0, bl, acc[0][ni]);
            acc[1][ni] = MFMA(ah1, bh, acc[1][ni]);
            acc[1][ni] = MFMA(al1, bh, acc[1][ni]);
            acc[1][ni] = MFMA(ah1, bl, acc[1][ni]);
        }
    }
    for (int kc = 0; kc < HSZ; kc += 32) {
        short8 ah0 = ld8(hp_hi + (size_t)row0 * HSZ + kc + quad * 8);
        short8 ah1 = ld8(hp_hi + (size_t)row1 * HSZ + kc + quad * 8);
        short8 al0 = ld8(hp_lo + (size_t)row0 * HSZ + kc + quad * 8);
        short8 al1 = ld8(hp_lo + (size_t)row1 * HSZ + kc + quad * 8);
#pragma unroll
        for (int ni = 0; ni < 2; ni++) {
            int n = nblk + ni * 16 + l15;
            short8 bh = ld8(Whh0hi + (size_t)n * HSZ + kc + quad * 8);
            short8 bl = ld8(Whh0lo + (size_t)n * HSZ + kc + quad * 8);
            acc[0][ni] = MFMA(ah0, bh, acc[0][ni]);
            acc[0][ni] = MFMA(al0, bh, acc[0][ni]);
            acc[0][ni] = MFMA(ah0, bl, acc[0][ni]);
            acc[1][ni] = MFMA(ah1, bh, acc[1][ni]);
            acc[1][ni] = MFMA(al1, bh, acc[1][ni]);
            acc[1][ni] = MFMA(ah1, bl, acc[1][ni]);
        }
    }
#pragma unroll
    for (int mi = 0; mi < 2; mi++) {
#pragma unroll
        for (int ni = 0; ni < 2; ni++) {
            int col = nblk + ni * 16 + l15;
            float bias = bih0[col] + bhh0[col];
#pragma unroll
            for (int r = 0; r < 4; r++) {
                int row = mblk + mi * 16 + quad * 4 + r;
                float v = tanhf(acc[mi][ni][r] + bias);
                bf16 hi = __float2bfloat16(v);
                hc_hi[(size_t)row * HSZ + col] = hi;
                hc_lo[(size_t)row * HSZ + col] = __float2bfloat16(v - b2f(hi));
            }
        }
    }
}

// ---- layer 1 tile: h1_t = tanh(h0_t @ Wih1 + h1_{t-1} @ Whh1 + b) ----
static __device__ __forceinline__ void step1_tile(
    int t, int fb, int wv, int lane,
    const bf16* __restrict__ Wih1hi, const bf16* __restrict__ Wih1lo,
    const bf16* __restrict__ Whh1hi, const bf16* __restrict__ Whh1lo,
    const float* __restrict__ bih1, const float* __restrict__ bhh1,
    const bf16* __restrict__ h0hi, const bf16* __restrict__ h0lo,
    bf16* __restrict__ h1hi, bf16* __restrict__ h1lo)
{
    const int l15 = lane & 15, quad = lane >> 4;
    const int rs = t & 1, wsl = rs ^ 1;
    const int mblk = (fb >> 3) * 64 + (wv >> 1) * 32;
    const int nblk = (fb & 7) * 64 + (wv & 1) * 32;

    const bf16* a0hi = h0hi + (size_t)wsl * (BSZ * HSZ);  // h0_t in slot (t&1)^1
    const bf16* a0lo = h0lo + (size_t)wsl * (BSZ * HSZ);
    const bf16* a1hi = h1hi + (size_t)rs * (BSZ * HSZ);   // h1_{t-1} in slot t&1
    const bf16* a1lo = h1lo + (size_t)rs * (BSZ * HSZ);
    bf16* hc_hi = h1hi + (size_t)wsl * (BSZ * HSZ);
    bf16* hc_lo = h1lo + (size_t)wsl * (BSZ * HSZ);

    const int row0 = mblk + l15, row1 = mblk + 16 + l15;
    f32x4 acc[2][2] = {};

    for (int kc = 0; kc < HSZ; kc += 32) {
        short8 p0 = ld8(a0hi + (size_t)row0 * HSZ + kc + quad * 8);
        short8 p1 = ld8(a0hi + (size_t)row1 * HSZ + kc + quad * 8);
        short8 q0 = ld8(a0lo + (size_t)row0 * HSZ + kc + quad * 8);
        short8 q1 = ld8(a0lo + (size_t)row1 * HSZ + kc + quad * 8);
        short8 r0 = ld8(a1hi + (size_t)row0 * HSZ + kc + quad * 8);
        short8 r1 = ld8(a1hi + (size_t)row1 * HSZ + kc + quad * 8);
        short8 s0 = ld8(a1lo + (size_t)row0 * HSZ + kc + quad * 8);
        short8 s1 = ld8(a1lo + (size_t)row1 * HSZ + kc + quad * 8);
#pragma unroll
        for (int ni = 0; ni < 2; ni++) {
            int n = nblk + ni * 16 + l15;
            short8 bih = ld8(Wih1hi + (size_t)n * HSZ + kc + quad * 8);
            short8 bil = ld8(Wih1lo + (size_t)n * HSZ + kc + quad * 8);
            short8 bhh = ld8(Whh1hi + (size_t)n * HSZ + kc + quad * 8);
            short8 bhl = ld8(Whh1lo + (size_t)n * HSZ + kc + quad * 8);
            acc[0][ni] = MFMA(p0, bih, acc[0][ni]);
            acc[0][ni] = MFMA(q0, bih, acc[0][ni]);
            acc[0][ni] = MFMA(p0, bil, acc[0][ni]);
            acc[0][ni] = MFMA(r0, bhh, acc[0][ni]);
            acc[0][ni] = MFMA(s0, bhh, acc[0][ni]);
            acc[0][ni] = MFMA(r0, bhl, acc[0][ni]);
            acc[1][ni] = MFMA(p1, bih, acc[1][ni]);
            acc[1][ni] = MFMA(q1, bih, acc[1][ni]);
            acc[1][ni] = MFMA(p1, bil, acc[1][ni]);
            acc[1][ni] = MFMA(r1, bhh, acc[1][ni]);
            acc[1][ni] = MFMA(s1, bhh, acc[1][ni]);
            acc[1][ni] = MFMA(r1, bhl, acc[1][ni]);
        }
    }
#pragma unroll
    for (int mi = 0; mi < 2; mi++) {
#pragma unroll
        for (int ni = 0; ni < 2; ni++) {
            int col = nblk + ni * 16 + l15;
            float bias = bih1[col] + bhh1[col];
#pragma unroll
            for (int r = 0; r < 4; r++) {
                int row = mblk + mi * 16 + quad * 4 + r;
                float v = tanhf(acc[mi][ni][r] + bias);
                bf16 hi = __float2bfloat16(v);
                hc_hi[(size_t)row * HSZ + col] = hi;
                hc_lo[(size_t)row * HSZ + col] = __float2bfloat16(v - b2f(hi));
            }
        }
    }
}

// ---- FC tile: logits[:, tout, :] = h1[tout] @ Wfc + b_fc ----
static __device__ __forceinline__ void fc_tile(
    int tout, int fb, int wv, int lane,
    const bf16* __restrict__ h1hi, const bf16* __restrict__ h1lo,
    const bf16* __restrict__ Wfchi, const bf16* __restrict__ Wfclo,
    const float* __restrict__ bfc, float* __restrict__ out)
{
    const int l15 = lane & 15, quad = lane >> 4;
    const int slot = (tout & 1) ^ 1;   // h1[tout] slot
    const bf16* hhi = h1hi + (size_t)slot * (BSZ * HSZ);
    const bf16* hlo = h1lo + (size_t)slot * (BSZ * HSZ);
    const int mblk = (fb >> 1) * 64 + (wv >> 1) * 32;
    const int nblk = (fb & 1) * 64 + (wv & 1) * 32;
    const int row0 = mblk + l15, row1 = mblk + 16 + l15;

    f32x4 acc[2][2] = {};
    for (int kc = 0; kc < HSZ; kc += 32) {
        short8 ah0 = ld8(hhi + (size_t)row0 * HSZ + kc + quad * 8);
        short8 ah1 = ld8(hhi + (size_t)row1 * HSZ + kc + quad * 8);
        short8 al0 = ld8(hlo + (size_t)row0 * HSZ + kc + quad * 8);
        short8 al1 = ld8(hlo + (size_t)row1 * HSZ + kc + quad * 8);
#pragma unroll
        for (int ni = 0; ni < 2; ni++) {
            int n = nblk + ni * 16 + l15;
            short8 bh = ld8(Wfchi + (size_t)n * HSZ + kc + quad * 8);
            short8 bl = ld8(Wfclo + (size_t)n * HSZ + kc + quad * 8);
            acc[0][ni] = MFMA(ah0, bh, acc[0][ni]);
            acc[0][ni] = MFMA(al0, bh, acc[0][ni]);
            acc[0][ni] = MFMA(ah0, bl, acc[0][ni]);
            acc[1][ni] = MFMA(ah1, bh, acc[1][ni]);
            acc[1][ni] = MFMA(al1, bh, acc[1][ni]);
            acc[1][ni] = MFMA(ah1, bl, acc[1][ni]);
        }
    }
#pragma unroll
    for (int mi = 0; mi < 2; mi++) {
#pragma unroll
        for (int ni = 0; ni < 2; ni++) {
            int col = nblk + ni * 16 + l15;
            float bias = bfc[col];
#pragma unroll
            for (int r = 0; r < 4; r++) {
                int row = mblk + mi * 16 + quad * 4 + r;
                out[((size_t)row * TLEN + tout) * VSZ + col] = acc[mi][ni][r] + bias;
            }
        }
    }
}

// ---- persistent kernel: 514 phases, grid barrier between phases ----
__global__ __launch_bounds__(256) void k_persist(
    const int* __restrict__ x,
    const float* __restrict__ bih0, const float* __restrict__ bhh0,
    const float* __restrict__ bih1, const float* __restrict__ bhh1,
    const float* __restrict__ bfc,
    bf16* __restrict__ ws, float* __restrict__ out)
{
    const int lane = threadIdx.x & 63;
    const int wv   = threadIdx.x >> 6;
    const int bid  = (int)blockIdx.x;

    unsigned int* bar = (unsigned int*)(ws + O_BAR);
    const bf16* embhi  = ws + O_EMBHI;  const bf16* emblo  = ws + O_EMBLO;
    const bf16* Wih0hi = ws + O_WIH0HI; const bf16* Wih0lo = ws + O_WIH0LO;
    const bf16* Whh0hi = ws + O_WHH0HI; const bf16* Whh0lo = ws + O_WHH0LO;
    const bf16* Wih1hi = ws + O_WIH1HI; const bf16* Wih1lo = ws + O_WIH1LO;
    const bf16* Whh1hi = ws + O_WHH1HI; const bf16* Whh1lo = ws + O_WHH1LO;
    const bf16* Wfchi  = ws + O_WFCHI;  const bf16* Wfclo  = ws + O_WFCLO;
    bf16* h0hi = ws + O_H0HI; bf16* h0lo = ws + O_H0LO;
    bf16* h1hi = ws + O_H1HI; bf16* h1lo = ws + O_H1LO;

    for (int p = 0; p < TLEN + 2; ++p) {
        if (bid < 32) {
            if (p < TLEN)
                step0_tile(p, bid, wv, lane, x, embhi, emblo, Wih0hi, Wih0lo,
                           Whh0hi, Whh0lo, bih0, bhh0, h0hi, h0lo);
        } else if (bid < 64) {
            int t = p - 1;
            if (t >= 0 && t < TLEN)
                step1_tile(t, bid - 32, wv, lane, Wih1hi, Wih1lo, Whh1hi, Whh1lo,
                           bih1, bhh1, h0hi, h0lo, h1hi, h1lo);
        } else {
            int tout = p - 2;
            if (tout >= 0)
                fc_tile(tout, bid - 64, wv, lane, h1hi, h1lo, Wfchi, Wfclo, bfc, out);
        }
        if (p < TLEN + 1) {
            __syncthreads();
            if (threadIdx.x == 0) {
                __hip_atomic_fetch_add(bar, 1u, __ATOMIC_RELEASE, __HIP_MEMORY_SCOPE_AGENT);
                const unsigned tgt = (unsigned)NBLK * (unsigned)(p + 1);
                unsigned v;
                do {
                    v = __hip_atomic_load(bar, __ATOMIC_ACQUIRE, __HIP_MEMORY_SCOPE_AGENT);
                    if (v < tgt) __builtin_amdgcn_s_sleep(4);
                } while (v < tgt);
            }
            __syncthreads();
        }
    }
}

extern "C" void kernel_launch(void* const* d_in, const int* in_sizes, int n_in,
                              void* d_out, int out_size, void* d_ws, size_t ws_size,
                              hipStream_t stream) {
    const int*   x    = (const int*)d_in[0];
    const float* emb  = (const float*)d_in[1];
    const float* Wih0 = (const float*)d_in[2];
    const float* bih0 = (const float*)d_in[3];
    const float* Whh0 = (const float*)d_in[4];
    const float* bhh0 = (const float*)d_in[5];
    const float* Wih1 = (const float*)d_in[6];
    const float* bih1 = (const float*)d_in[7];
    const float* Whh1 = (const float*)d_in[8];
    const float* bhh1 = (const float*)d_in[9];
    const float* Wfc  = (const float*)d_in[10];
    const float* bfc  = (const float*)d_in[11];
    float* out = (float*)d_out;
    bf16* ws   = (bf16*)d_ws;

    // one prep launch: all splits/transposes + zero h slabs + zero barrier
    const int total = 3 * HSZ * HSZ + HSZ * EMBD + VSZ * HSZ + VSZ * EMBD
                    + (8 * BSZ * HSZ) / 2 + 64;
    k_prep<<<(total + 255) / 256, 256, 0, stream>>>(emb, Wih0, Whh0, Wih1, Whh1, Wfc, ws);

    // one persistent launch for the whole recurrence + FC
    k_persist<<<NBLK, 256, 0, stream>>>(x, bih0, bhh0, bih1, bhh1, bfc, ws, out);
}

// Round 4
// 13533.182 us; speedup vs baseline: 2.0687x; 1.5199x over previous
//
#include <hip/hip_runtime.h>
#include <hip/hip_bf16.h>

#define VSZ 128
#define EMBD 64
#define HSZ 512
#define BSZ 256
#define TLEN 512
#define NB0 32            // layer0 blocks (64x64 tiles)
#define NB1 64            // layer1 blocks (32x64 tiles)
#define NBFC 8            // fc blocks (64x64 tiles)
#define NBLK (NB0 + NB1 + NBFC)   // 104

typedef __attribute__((ext_vector_type(8))) short short8;
typedef __attribute__((ext_vector_type(4))) float f32x4;
typedef __hip_bfloat16 bf16;

// ---- workspace layout (bf16 element offsets) ----
#define O_WHH0HI ((size_t)0)
#define O_WHH0LO (O_WHH0HI + (size_t)HSZ*HSZ)
#define O_WIH1HI (O_WHH0LO + (size_t)HSZ*HSZ)
#define O_WIH1LO (O_WIH1HI + (size_t)HSZ*HSZ)
#define O_WHH1HI (O_WIH1LO + (size_t)HSZ*HSZ)
#define O_WHH1LO (O_WHH1HI + (size_t)HSZ*HSZ)
#define O_WIH0HI (O_WHH1LO + (size_t)HSZ*HSZ)     // [N=512][K=64]
#define O_WIH0LO (O_WIH0HI + (size_t)HSZ*EMBD)
#define O_WFCHI  (O_WIH0LO + (size_t)HSZ*EMBD)    // [N=128][K=512]
#define O_WFCLO  (O_WFCHI + (size_t)VSZ*HSZ)
#define O_EMBHI  (O_WFCLO + (size_t)VSZ*HSZ)      // [128][64] row-major
#define O_EMBLO  (O_EMBHI + (size_t)VSZ*EMBD)
#define O_H0HI   (O_EMBLO + (size_t)VSZ*EMBD)     // [2][256][512] ping-pong
#define O_H0LO   (O_H0HI + (size_t)2*BSZ*HSZ)
#define O_H1HI   (O_H0LO + (size_t)2*BSZ*HSZ)
#define O_H1LO   (O_H1HI + (size_t)2*BSZ*HSZ)
#define O_FLAGS  (O_H1LO + (size_t)2*BSZ*HSZ)     // 128 slots x 32 u32 (128B pad)

static __device__ __forceinline__ short8 ld8(const bf16* p) {
    return *(const short8*)p;
}
static __device__ __forceinline__ float b2f(bf16 v) { return __bfloat162float(v); }

#define MFMA(a,b,c) __builtin_amdgcn_mfma_f32_16x16x32_bf16((a),(b),(c),0,0,0)

// ---- one prep kernel: split/transpose weights + zero state + init flags ----
__global__ void k_prep(const float* __restrict__ emb, const float* __restrict__ Wih0,
                       const float* __restrict__ Whh0, const float* __restrict__ Wih1,
                       const float* __restrict__ Whh1, const float* __restrict__ Wfc,
                       bf16* __restrict__ ws) {
    int j = blockIdx.x * blockDim.x + threadIdx.x;
    const int SQ = HSZ * HSZ;              // 262144
    if (j < SQ) {          // Whh0T
        int n = j / HSZ, k = j - n * HSZ;
        float w = Whh0[k * HSZ + n];
        bf16 hi = __float2bfloat16(w);
        ws[O_WHH0HI + j] = hi; ws[O_WHH0LO + j] = __float2bfloat16(w - b2f(hi));
        return;
    }
    j -= SQ;
    if (j < SQ) {          // Wih1T
        int n = j / HSZ, k = j - n * HSZ;
        float w = Wih1[k * HSZ + n];
        bf16 hi = __float2bfloat16(w);
        ws[O_WIH1HI + j] = hi; ws[O_WIH1LO + j] = __float2bfloat16(w - b2f(hi));
        return;
    }
    j -= SQ;
    if (j < SQ) {          // Whh1T
        int n = j / HSZ, k = j - n * HSZ;
        float w = Whh1[k * HSZ + n];
        bf16 hi = __float2bfloat16(w);
        ws[O_WHH1HI + j] = hi; ws[O_WHH1LO + j] = __float2bfloat16(w - b2f(hi));
        return;
    }
    j -= SQ;
    if (j < HSZ * EMBD) {  // Wih0T: out [512][64], in [64][512]
        int n = j / EMBD, k = j - n * EMBD;
        float w = Wih0[k * HSZ + n];
        bf16 hi = __float2bfloat16(w);
        ws[O_WIH0HI + j] = hi; ws[O_WIH0LO + j] = __float2bfloat16(w - b2f(hi));
        return;
    }
    j -= HSZ * EMBD;
    if (j < VSZ * HSZ) {   // WfcT: out [128][512], in [512][128]
        int n = j / HSZ, k = j - n * HSZ;
        float w = Wfc[k * VSZ + n];
        bf16 hi = __float2bfloat16(w);
        ws[O_WFCHI + j] = hi; ws[O_WFCLO + j] = __float2bfloat16(w - b2f(hi));
        return;
    }
    j -= VSZ * HSZ;
    if (j < VSZ * EMBD) {  // emb split
        float w = emb[j];
        bf16 hi = __float2bfloat16(w);
        ws[O_EMBHI + j] = hi; ws[O_EMBLO + j] = __float2bfloat16(w - b2f(hi));
        return;
    }
    j -= VSZ * EMBD;
    const int NZ = (8 * BSZ * HSZ) / 2;    // h slabs as u32
    if (j < NZ) {
        ((unsigned int*)(ws + O_H0HI))[j] = 0u;
        return;
    }
    j -= NZ;
    if (j < 128 * 32) {    // flags: slot<NBLK -> 0, else huge
        int slot = j >> 5;
        ((unsigned int*)(ws + O_FLAGS))[j] = (slot < NBLK) ? 0u : 0x7FFFFFFFu;
    }
}

// ---- contention-free grid barrier: padded per-block flags, relaxed polls ----
static __device__ __forceinline__ void grid_barrier(unsigned int* flags, int bid, int p) {
    __syncthreads();
    if (threadIdx.x == 0) {
        __builtin_amdgcn_fence(__ATOMIC_RELEASE, "agent");
        __hip_atomic_store(&flags[bid * 32], (unsigned)(p + 1),
                           __ATOMIC_RELAXED, __HIP_MEMORY_SCOPE_AGENT);
    }
    if (threadIdx.x < 64) {
        const unsigned tgt = (unsigned)(p + 1);
        for (;;) {
            unsigned a = __hip_atomic_load(&flags[threadIdx.x * 32],
                                           __ATOMIC_RELAXED, __HIP_MEMORY_SCOPE_AGENT);
            unsigned b = __hip_atomic_load(&flags[(threadIdx.x + 64) * 32],
                                           __ATOMIC_RELAXED, __HIP_MEMORY_SCOPE_AGENT);
            if (__all(a >= tgt && b >= tgt)) break;
            __builtin_amdgcn_s_sleep(1);
        }
        if (threadIdx.x == 0)
            __builtin_amdgcn_fence(__ATOMIC_ACQUIRE, "agent");
    }
    __syncthreads();
}

// ---- layer 0 tile: 64x64 block tile, wave 32x32, dual accumulators ----
static __device__ __forceinline__ void step0_tile(
    int t, int fb, int wv, int lane,
    const int* __restrict__ x,
    const bf16* __restrict__ embhi, const bf16* __restrict__ emblo,
    const bf16* __restrict__ Wih0hi, const bf16* __restrict__ Wih0lo,
    const bf16* __restrict__ Whh0hi, const bf16* __restrict__ Whh0lo,
    const float* __restrict__ bih0, const float* __restrict__ bhh0,
    bf16* __restrict__ h0hi, bf16* __restrict__ h0lo)
{
    const int l15 = lane & 15, quad = lane >> 4;
    const int rs = t & 1, wsl = rs ^ 1;
    const int mblk = (fb >> 3) * 64 + (wv >> 1) * 32;
    const int nblk = (fb & 7) * 64 + (wv & 1) * 32;

    const bf16* hp_hi = h0hi + (size_t)rs * (BSZ * HSZ);
    const bf16* hp_lo = h0lo + (size_t)rs * (BSZ * HSZ);
    bf16* hc_hi = h0hi + (size_t)wsl * (BSZ * HSZ);
    bf16* hc_lo = h0lo + (size_t)wsl * (BSZ * HSZ);

    f32x4 accA[2][2] = {}, accB[2][2] = {};
    const int row0 = mblk + l15, row1 = mblk + 16 + l15;

    const int x0 = x[row0 * TLEN + t];
    const int x1 = x[row1 * TLEN + t];
#pragma unroll
    for (int kc = 0; kc < EMBD; kc += 32) {
        short8 ah0 = ld8(embhi + (size_t)x0 * EMBD + kc + quad * 8);
        short8 ah1 = ld8(embhi + (size_t)x1 * EMBD + kc + quad * 8);
        short8 al0 = ld8(emblo + (size_t)x0 * EMBD + kc + quad * 8);
        short8 al1 = ld8(emblo + (size_t)x1 * EMBD + kc + quad * 8);
#pragma unroll
        for (int ni = 0; ni < 2; ni++) {
            int n = nblk + ni * 16 + l15;
            short8 bh = ld8(Wih0hi + (size_t)n * EMBD + kc + quad * 8);
            short8 bl = ld8(Wih0lo + (size_t)n * EMBD + kc + quad * 8);
            accA[0][ni] = MFMA(ah0, bh, accA[0][ni]);
            accB[0][ni] = MFMA(al0, bh, accB[0][ni]);
            accB[0][ni] = MFMA(ah0, bl, accB[0][ni]);
            accA[1][ni] = MFMA(ah1, bh, accA[1][ni]);
            accB[1][ni] = MFMA(al1, bh, accB[1][ni]);
            accB[1][ni] = MFMA(ah1, bl, accB[1][ni]);
        }
    }
    for (int kc = 0; kc < HSZ; kc += 32) {
        short8 ah0 = ld8(hp_hi + (size_t)row0 * HSZ + kc + quad * 8);
        short8 ah1 = ld8(hp_hi + (size_t)row1 * HSZ + kc + quad * 8);
        short8 al0 = ld8(hp_lo + (size_t)row0 * HSZ + kc + quad * 8);
        short8 al1 = ld8(hp_lo + (size_t)row1 * HSZ + kc + quad * 8);
#pragma unroll
        for (int ni = 0; ni < 2; ni++) {
            int n = nblk + ni * 16 + l15;
            short8 bh = ld8(Whh0hi + (size_t)n * HSZ + kc + quad * 8);
            short8 bl = ld8(Whh0lo + (size_t)n * HSZ + kc + quad * 8);
            accA[0][ni] = MFMA(ah0, bh, accA[0][ni]);
            accB[0][ni] = MFMA(al0, bh, accB[0][ni]);
            accB[0][ni] = MFMA(ah0, bl, accB[0][ni]);
            accA[1][ni] = MFMA(ah1, bh, accA[1][ni]);
            accB[1][ni] = MFMA(al1, bh, accB[1][ni]);
            accB[1][ni] = MFMA(ah1, bl, accB[1][ni]);
        }
    }
#pragma unroll
    for (int mi = 0; mi < 2; mi++) {
#pragma unroll
        for (int ni = 0; ni < 2; ni++) {
            int col = nblk + ni * 16 + l15;
            float bias = bih0[col] + bhh0[col];
#pragma unroll
            for (int r = 0; r < 4; r++) {
                int row = mblk + mi * 16 + quad * 4 + r;
                float v = tanhf(accA[mi][ni][r] + accB[mi][ni][r] + bias);
                bf16 hi = __float2bfloat16(v);
                hc_hi[(size_t)row * HSZ + col] = hi;
                hc_lo[(size_t)row * HSZ + col] = __float2bfloat16(v - b2f(hi));
            }
        }
    }
}

// ---- layer 1 tile: 32x64 block tile (64 blocks), wave 16x32, dual acc ----
static __device__ __forceinline__ void step1_tile(
    int t, int fb, int wv, int lane,
    const bf16* __restrict__ Wih1hi, const bf16* __restrict__ Wih1lo,
    const bf16* __restrict__ Whh1hi, const bf16* __restrict__ Whh1lo,
    const float* __restrict__ bih1, const float* __restrict__ bhh1,
    const bf16* __restrict__ h0hi, const bf16* __restrict__ h0lo,
    bf16* __restrict__ h1hi, bf16* __restrict__ h1lo)
{
    const int l15 = lane & 15, quad = lane >> 4;
    const int rs = t & 1, wsl = rs ^ 1;
    const int mrow = (fb >> 3) * 32 + (wv >> 1) * 16;   // 16-row wave tile
    const int ncol = (fb & 7) * 64 + (wv & 1) * 32;

    const bf16* a0hi = h0hi + (size_t)wsl * (BSZ * HSZ);  // h0_t
    const bf16* a0lo = h0lo + (size_t)wsl * (BSZ * HSZ);
    const bf16* a1hi = h1hi + (size_t)rs * (BSZ * HSZ);   // h1_{t-1}
    const bf16* a1lo = h1lo + (size_t)rs * (BSZ * HSZ);
    bf16* hc_hi = h1hi + (size_t)wsl * (BSZ * HSZ);
    bf16* hc_lo = h1lo + (size_t)wsl * (BSZ * HSZ);

    const int row0 = mrow + l15;
    f32x4 accA[2] = {}, accB[2] = {};

    for (int kc = 0; kc < HSZ; kc += 32) {
        short8 p0 = ld8(a0hi + (size_t)row0 * HSZ + kc + quad * 8);
        short8 q0 = ld8(a0lo + (size_t)row0 * HSZ + kc + quad * 8);
        short8 r0 = ld8(a1hi + (size_t)row0 * HSZ + kc + quad * 8);
        short8 s0 = ld8(a1lo + (size_t)row0 * HSZ + kc + quad * 8);
#pragma unroll
        for (int ni = 0; ni < 2; ni++) {
            int n = ncol + ni * 16 + l15;
            short8 bih = ld8(Wih1hi + (size_t)n * HSZ + kc + quad * 8);
            short8 bil = ld8(Wih1lo + (size_t)n * HSZ + kc + quad * 8);
            short8 bhh = ld8(Whh1hi + (size_t)n * HSZ + kc + quad * 8);
            short8 bhl = ld8(Whh1lo + (size_t)n * HSZ + kc + quad * 8);
            accA[ni] = MFMA(p0, bih, accA[ni]);
            accA[ni] = MFMA(r0, bhh, accA[ni]);
            accB[ni] = MFMA(q0, bih, accB[ni]);
            accB[ni] = MFMA(p0, bil, accB[ni]);
            accB[ni] = MFMA(s0, bhh, accB[ni]);
            accB[ni] = MFMA(r0, bhl, accB[ni]);
        }
    }
#pragma unroll
    for (int ni = 0; ni < 2; ni++) {
        int col = ncol + ni * 16 + l15;
        float bias = bih1[col] + bhh1[col];
#pragma unroll
        for (int r = 0; r < 4; r++) {
            int row = mrow + quad * 4 + r;
            float v = tanhf(accA[ni][r] + accB[ni][r] + bias);
            bf16 hi = __float2bfloat16(v);
            hc_hi[(size_t)row * HSZ + col] = hi;
            hc_lo[(size_t)row * HSZ + col] = __float2bfloat16(v - b2f(hi));
        }
    }
}

// ---- FC tile: 64x64 block tile (8 blocks), wave 32x32, dual acc ----
static __device__ __forceinline__ void fc_tile(
    int tout, int fb, int wv, int lane,
    const bf16* __restrict__ h1hi, const bf16* __restrict__ h1lo,
    const bf16* __restrict__ Wfchi, const bf16* __restrict__ Wfclo,
    const float* __restrict__ bfc, float* __restrict__ out)
{
    const int l15 = lane & 15, quad = lane >> 4;
    const int slot = (tout & 1) ^ 1;
    const bf16* hhi = h1hi + (size_t)slot * (BSZ * HSZ);
    const bf16* hlo = h1lo + (size_t)slot * (BSZ * HSZ);
    const int mblk = (fb >> 1) * 64 + (wv >> 1) * 32;
    const int nblk = (fb & 1) * 64 + (wv & 1) * 32;
    const int row0 = mblk + l15, row1 = mblk + 16 + l15;

    f32x4 accA[2][2] = {}, accB[2][2] = {};
    for (int kc = 0; kc < HSZ; kc += 32) {
        short8 ah0 = ld8(hhi + (size_t)row0 * HSZ + kc + quad * 8);
        short8 ah1 = ld8(hhi + (size_t)row1 * HSZ + kc + quad * 8);
        short8 al0 = ld8(hlo + (size_t)row0 * HSZ + kc + quad * 8);
        short8 al1 = ld8(hlo + (size_t)row1 * HSZ + kc + quad * 8);
#pragma unroll
        for (int ni = 0; ni < 2; ni++) {
            int n = nblk + ni * 16 + l15;
            short8 bh = ld8(Wfchi + (size_t)n * HSZ + kc + quad * 8);
            short8 bl = ld8(Wfclo + (size_t)n * HSZ + kc + quad * 8);
            accA[0][ni] = MFMA(ah0, bh, accA[0][ni]);
            accB[0][ni] = MFMA(al0, bh, accB[0][ni]);
            accB[0][ni] = MFMA(ah0, bl, accB[0][ni]);
            accA[1][ni] = MFMA(ah1, bh, accA[1][ni]);
            accB[1][ni] = MFMA(al1, bh, accB[1][ni]);
            accB[1][ni] = MFMA(ah1, bl, accB[1][ni]);
        }
    }
#pragma unroll
    for (int mi = 0; mi < 2; mi++) {
#pragma unroll
        for (int ni = 0; ni < 2; ni++) {
            int col = nblk + ni * 16 + l15;
            float bias = bfc[col];
#pragma unroll
            for (int r = 0; r < 4; r++) {
                int row = mblk + mi * 16 + quad * 4 + r;
                out[((size_t)row * TLEN + tout) * VSZ + col] =
                    accA[mi][ni][r] + accB[mi][ni][r] + bias;
            }
        }
    }
}

// ---- persistent kernel: 514 phases, flag barrier between phases ----
__global__ __launch_bounds__(256) void k_persist(
    const int* __restrict__ x,
    const float* __restrict__ bih0, const float* __restrict__ bhh0,
    const float* __restrict__ bih1, const float* __restrict__ bhh1,
    const float* __restrict__ bfc,
    bf16* __restrict__ ws, float* __restrict__ out)
{
    const int lane = threadIdx.x & 63;
    const int wv   = threadIdx.x >> 6;
    const int bid  = (int)blockIdx.x;

    unsigned int* flags = (unsigned int*)(ws + O_FLAGS);
    const bf16* embhi  = ws + O_EMBHI;  const bf16* emblo  = ws + O_EMBLO;
    const bf16* Wih0hi = ws + O_WIH0HI; const bf16* Wih0lo = ws + O_WIH0LO;
    const bf16* Whh0hi = ws + O_WHH0HI; const bf16* Whh0lo = ws + O_WHH0LO;
    const bf16* Wih1hi = ws + O_WIH1HI; const bf16* Wih1lo = ws + O_WIH1LO;
    const bf16* Whh1hi = ws + O_WHH1HI; const bf16* Whh1lo = ws + O_WHH1LO;
    const bf16* Wfchi  = ws + O_WFCHI;  const bf16* Wfclo  = ws + O_WFCLO;
    bf16* h0hi = ws + O_H0HI; bf16* h0lo = ws + O_H0LO;
    bf16* h1hi = ws + O_H1HI; bf16* h1lo = ws + O_H1LO;

    for (int p = 0; p < TLEN + 2; ++p) {
        if (bid < NB0) {
            if (p < TLEN)
                step0_tile(p, bid, wv, lane, x, embhi, emblo, Wih0hi, Wih0lo,
                           Whh0hi, Whh0lo, bih0, bhh0, h0hi, h0lo);
        } else if (bid < NB0 + NB1) {
            int t = p - 1;
            if (t >= 0 && t < TLEN)
                step1_tile(t, bid - NB0, wv, lane, Wih1hi, Wih1lo, Whh1hi, Whh1lo,
                           bih1, bhh1, h0hi, h0lo, h1hi, h1lo);
        } else {
            int tout = p - 2;
            if (tout >= 0)
                fc_tile(tout, bid - NB0 - NB1, wv, lane, h1hi, h1lo,
                        Wfchi, Wfclo, bfc, out);
        }
        if (p < TLEN + 1)
            grid_barrier(flags, bid, p);
    }
}

extern "C" void kernel_launch(void* const* d_in, const int* in_sizes, int n_in,
                              void* d_out, int out_size, void* d_ws, size_t ws_size,
                              hipStream_t stream) {
    const int*   x    = (const int*)d_in[0];
    const float* emb  = (const float*)d_in[1];
    const float* Wih0 = (const float*)d_in[2];
    const float* bih0 = (const float*)d_in[3];
    const float* Whh0 = (const float*)d_in[4];
    const float* bhh0 = (const float*)d_in[5];
    const float* Wih1 = (const float*)d_in[6];
    const float* bih1 = (const float*)d_in[7];
    const float* Whh1 = (const float*)d_in[8];
    const float* bhh1 = (const float*)d_in[9];
    const float* Wfc  = (const float*)d_in[10];
    const float* bfc  = (const float*)d_in[11];
    float* out = (float*)d_out;
    bf16* ws   = (bf16*)d_ws;

    const int total = 3 * HSZ * HSZ + HSZ * EMBD + VSZ * HSZ + VSZ * EMBD
                    + (8 * BSZ * HSZ) / 2 + 128 * 32;
    k_prep<<<(total + 255) / 256, 256, 0, stream>>>(emb, Wih0, Whh0, Wih1, Whh1, Wfc, ws);

    k_persist<<<NBLK, 256, 0, stream>>>(x, bih0, bhh0, bih1, bhh1, bfc, ws, out);
}

// Round 5
// 11351.765 us; speedup vs baseline: 2.4662x; 1.1922x over previous
//
#include <hip/hip_runtime.h>
#include <hip/hip_bf16.h>

#define VSZ 128
#define EMBD 64
#define HSZ 512
#define BSZ 256
#define TLEN 512
#define NB0 32            // layer0 blocks: 16 rows x 256 cols
#define NB1 64            // layer1 blocks: 16 rows x 128 cols
#define NBFC 8            // fc blocks:     32 rows x 128 cols
#define NBLK (NB0 + NB1 + NBFC)   // 104

typedef __attribute__((ext_vector_type(8))) short short8;
typedef __attribute__((ext_vector_type(4))) float f32x4;
typedef __hip_bfloat16 bf16;

// ---- workspace layout (bf16 element offsets) ----
#define O_WHH0HI ((size_t)0)
#define O_WHH0LO (O_WHH0HI + (size_t)HSZ*HSZ)
#define O_WIH1HI (O_WHH0LO + (size_t)HSZ*HSZ)
#define O_WIH1LO (O_WIH1HI + (size_t)HSZ*HSZ)
#define O_WHH1HI (O_WIH1LO + (size_t)HSZ*HSZ)
#define O_WHH1LO (O_WHH1HI + (size_t)HSZ*HSZ)
#define O_WIH0HI (O_WHH1LO + (size_t)HSZ*HSZ)     // [N=512][K=64]
#define O_WIH0LO (O_WIH0HI + (size_t)HSZ*EMBD)
#define O_WFCHI  (O_WIH0LO + (size_t)HSZ*EMBD)    // [N=128][K=512]
#define O_WFCLO  (O_WFCHI + (size_t)VSZ*HSZ)
#define O_EMBHI  (O_WFCLO + (size_t)VSZ*HSZ)      // [128][64] row-major
#define O_EMBLO  (O_EMBHI + (size_t)VSZ*EMBD)
#define O_H0HI   (O_EMBLO + (size_t)VSZ*EMBD)     // [2][256][512] ping-pong
#define O_H0LO   (O_H0HI + (size_t)2*BSZ*HSZ)
#define O_H1HI   (O_H0LO + (size_t)2*BSZ*HSZ)
#define O_H1LO   (O_H1HI + (size_t)2*BSZ*HSZ)
#define O_FLAGS  (O_H1LO + (size_t)2*BSZ*HSZ)     // 128 slots x 32 u32 (128B pad)

static __device__ __forceinline__ short8 ld8(const bf16* p) {
    return *(const short8*)p;
}
static __device__ __forceinline__ float b2f(bf16 v) { return __bfloat162float(v); }

#define MFMA(a,b,c) __builtin_amdgcn_mfma_f32_16x16x32_bf16((a),(b),(c),0,0,0)

// ---- coherent (LLC read/write-through) primitives: the ONLY cross-XCD traffic ----
static __device__ __forceinline__ void ld8sc(
    const bf16* p0, const bf16* p1, const bf16* p2, const bf16* p3,
    const bf16* p4, const bf16* p5, const bf16* p6, const bf16* p7, short8* o)
{
    asm volatile(
        "global_load_dwordx4 %0, %8, off sc0 sc1\n\t"
        "global_load_dwordx4 %1, %9, off sc0 sc1\n\t"
        "global_load_dwordx4 %2, %10, off sc0 sc1\n\t"
        "global_load_dwordx4 %3, %11, off sc0 sc1\n\t"
        "global_load_dwordx4 %4, %12, off sc0 sc1\n\t"
        "global_load_dwordx4 %5, %13, off sc0 sc1\n\t"
        "global_load_dwordx4 %6, %14, off sc0 sc1\n\t"
        "global_load_dwordx4 %7, %15, off sc0 sc1\n\t"
        "s_waitcnt vmcnt(0)"
        : "=&v"(o[0]), "=&v"(o[1]), "=&v"(o[2]), "=&v"(o[3]),
          "=&v"(o[4]), "=&v"(o[5]), "=&v"(o[6]), "=&v"(o[7])
        : "v"(p0), "v"(p1), "v"(p2), "v"(p3), "v"(p4), "v"(p5), "v"(p6), "v"(p7)
        : "memory");
}

static __device__ __forceinline__ void st2_sc(bf16* p, bf16 v) {
    unsigned short us;
    __builtin_memcpy(&us, &v, 2);
    unsigned u = us;
    asm volatile("global_store_short %0, %1, off sc0 sc1" :: "v"(p), "v"(u) : "memory");
}

// ---- one prep kernel: split/transpose weights + zero state + init flags ----
__global__ void k_prep(const float* __restrict__ emb, const float* __restrict__ Wih0,
                       const float* __restrict__ Whh0, const float* __restrict__ Wih1,
                       const float* __restrict__ Whh1, const float* __restrict__ Wfc,
                       bf16* __restrict__ ws) {
    int j = blockIdx.x * blockDim.x + threadIdx.x;
    const int SQ = HSZ * HSZ;
    if (j < SQ) {          // Whh0T
        int n = j / HSZ, k = j - n * HSZ;
        float w = Whh0[k * HSZ + n];
        bf16 hi = __float2bfloat16(w);
        ws[O_WHH0HI + j] = hi; ws[O_WHH0LO + j] = __float2bfloat16(w - b2f(hi));
        return;
    }
    j -= SQ;
    if (j < SQ) {          // Wih1T
        int n = j / HSZ, k = j - n * HSZ;
        float w = Wih1[k * HSZ + n];
        bf16 hi = __float2bfloat16(w);
        ws[O_WIH1HI + j] = hi; ws[O_WIH1LO + j] = __float2bfloat16(w - b2f(hi));
        return;
    }
    j -= SQ;
    if (j < SQ) {          // Whh1T
        int n = j / HSZ, k = j - n * HSZ;
        float w = Whh1[k * HSZ + n];
        bf16 hi = __float2bfloat16(w);
        ws[O_WHH1HI + j] = hi; ws[O_WHH1LO + j] = __float2bfloat16(w - b2f(hi));
        return;
    }
    j -= SQ;
    if (j < HSZ * EMBD) {  // Wih0T: out [512][64], in [64][512]
        int n = j / EMBD, k = j - n * EMBD;
        float w = Wih0[k * HSZ + n];
        bf16 hi = __float2bfloat16(w);
        ws[O_WIH0HI + j] = hi; ws[O_WIH0LO + j] = __float2bfloat16(w - b2f(hi));
        return;
    }
    j -= HSZ * EMBD;
    if (j < VSZ * HSZ) {   // WfcT: out [128][512], in [512][128]
        int n = j / HSZ, k = j - n * HSZ;
        float w = Wfc[k * VSZ + n];
        bf16 hi = __float2bfloat16(w);
        ws[O_WFCHI + j] = hi; ws[O_WFCLO + j] = __float2bfloat16(w - b2f(hi));
        return;
    }
    j -= VSZ * HSZ;
    if (j < VSZ * EMBD) {  // emb split
        float w = emb[j];
        bf16 hi = __float2bfloat16(w);
        ws[O_EMBHI + j] = hi; ws[O_EMBLO + j] = __float2bfloat16(w - b2f(hi));
        return;
    }
    j -= VSZ * EMBD;
    const int NZ = (8 * BSZ * HSZ) / 2;    // h slabs as u32
    if (j < NZ) {
        ((unsigned int*)(ws + O_H0HI))[j] = 0u;
        return;
    }
    j -= NZ;
    if (j < 128 * 32) {    // flags: slot<NBLK -> 0, else huge
        int slot = j >> 5;
        ((unsigned int*)(ws + O_FLAGS))[j] = (slot < NBLK) ? 0u : 0x7FFFFFFFu;
    }
}

// ---- fence-free grid barrier: per-wave store-drain + sc flag store + sc poll ----
static __device__ __forceinline__ void grid_barrier(unsigned int* flags, int bid, int p) {
    asm volatile("s_waitcnt vmcnt(0)" ::: "memory");   // drain this wave's sc stores
    __syncthreads();                                   // all waves drained
    if (threadIdx.x == 0) {
        unsigned val = (unsigned)(p + 1);
        asm volatile("global_store_dword %0, %1, off sc0 sc1"
                     :: "v"(&flags[bid * 32]), "v"(val) : "memory");
    }
    if (threadIdx.x < 64) {
        const unsigned tgt = (unsigned)(p + 1);
        const unsigned* pa = &flags[threadIdx.x * 32];
        const unsigned* pb = &flags[(threadIdx.x + 64) * 32];
        for (;;) {
            unsigned a, b;
            asm volatile("global_load_dword %0, %2, off sc0 sc1\n\t"
                         "global_load_dword %1, %3, off sc0 sc1\n\t"
                         "s_waitcnt vmcnt(0)"
                         : "=&v"(a), "=&v"(b) : "v"(pa), "v"(pb) : "memory");
            if (__all(a >= tgt && b >= tgt)) break;
            __builtin_amdgcn_s_sleep(1);
        }
    }
    __syncthreads();
}

// stage one 16-row slab quarter-set: thread's 4 chunks of `src` (slab base at its
// 16-row window) into LDS fragment-order. goff/lds offsets computed by caller.

// ---- persistent kernel ----
__global__ __launch_bounds__(256) void k_persist(
    const int* __restrict__ x,
    const float* __restrict__ bih0, const float* __restrict__ bhh0,
    const float* __restrict__ bih1, const float* __restrict__ bhh1,
    const float* __restrict__ bfc,
    bf16* __restrict__ ws, float* __restrict__ out)
{
    extern __shared__ char smem[];
    const int tid  = (int)threadIdx.x;
    const int lane = tid & 63;
    const int wv   = tid >> 6;
    const int l15  = lane & 15;
    const int quad = lane >> 4;
    const int bid  = (int)blockIdx.x;

    unsigned int* flags = (unsigned int*)(ws + O_FLAGS);
    const bf16* embhi  = ws + O_EMBHI;  const bf16* emblo  = ws + O_EMBLO;
    const bf16* Wih0hi = ws + O_WIH0HI; const bf16* Wih0lo = ws + O_WIH0LO;
    const bf16* Whh0hi = ws + O_WHH0HI; const bf16* Whh0lo = ws + O_WHH0LO;
    const bf16* Wih1hi = ws + O_WIH1HI; const bf16* Wih1lo = ws + O_WIH1LO;
    const bf16* Whh1hi = ws + O_WHH1HI; const bf16* Whh1lo = ws + O_WHH1LO;
    const bf16* Wfchi  = ws + O_WFCHI;  const bf16* Wfclo  = ws + O_WFCLO;
    bf16* h0hi = ws + O_H0HI; bf16* h0lo = ws + O_H0LO;
    bf16* h1hi = ws + O_H1HI; bf16* h1lo = ws + O_H1LO;

    // staging address pattern: chunk c = tid + 256*i, lane_c = c&63 (== lane),
    // kc = c>>6; global elem offset within slab = (lane&15)*HSZ + kc*32 + quad*8
    const size_t goff = (size_t)l15 * HSZ + (tid >> 6) * 32 + quad * 8;

    for (int p = 0; p < TLEN + 2; ++p) {
        if (bid < NB0) {
            // ---- layer0: 16 rows x 256 cols ----
            if (p < TLEN) {
                const int t = p;
                const int rs = t & 1, wsl = rs ^ 1;
                const int mb = (bid >> 1) * 16;
                const int colbase = (bid & 1) * 256 + wv * 64;
                const bf16* sp0 = h0hi + (size_t)rs * (BSZ * HSZ) + (size_t)mb * HSZ;
                const bf16* sp1 = h0lo + (size_t)rs * (BSZ * HSZ) + (size_t)mb * HSZ;
                bf16* hc_hi = h0hi + (size_t)wsl * (BSZ * HSZ);
                bf16* hc_lo = h0lo + (size_t)wsl * (BSZ * HSZ);

                short8 v[8];
                ld8sc(sp0 + goff, sp0 + goff + 128, sp0 + goff + 256, sp0 + goff + 384,
                      sp1 + goff, sp1 + goff + 128, sp1 + goff + 256, sp1 + goff + 384, v);
#pragma unroll
                for (int i = 0; i < 4; i++) {
                    *(short8*)(smem + 0 * 16384 + tid * 16 + i * 4096) = v[i];
                    *(short8*)(smem + 1 * 16384 + tid * 16 + i * 4096) = v[4 + i];
                }
                __syncthreads();

                const int xr = x[(mb + l15) * TLEN + t];
                f32x4 accA[4] = {}, accB[4] = {};
                // emb-gather GEMM, K=64
#pragma unroll
                for (int kc2 = 0; kc2 < 2; kc2++) {
                    short8 eh = ld8(embhi + (size_t)xr * EMBD + kc2 * 32 + quad * 8);
                    short8 el = ld8(emblo + (size_t)xr * EMBD + kc2 * 32 + quad * 8);
#pragma unroll
                    for (int ni = 0; ni < 4; ni++) {
                        int n = colbase + ni * 16 + l15;
                        short8 bh = ld8(Wih0hi + (size_t)n * EMBD + kc2 * 32 + quad * 8);
                        short8 bl = ld8(Wih0lo + (size_t)n * EMBD + kc2 * 32 + quad * 8);
                        accA[ni] = MFMA(eh, bh, accA[ni]);
                        accB[ni] = MFMA(el, bh, accB[ni]);
                        accB[ni] = MFMA(eh, bl, accB[ni]);
                    }
                }
                // hh GEMM, K=512, A from LDS
                for (int kc = 0; kc < 16; kc++) {
                    const int coff = (kc * 64 + lane) * 16;
                    short8 ah = *(const short8*)(smem + 0 * 16384 + coff);
                    short8 al = *(const short8*)(smem + 1 * 16384 + coff);
#pragma unroll
                    for (int ni = 0; ni < 4; ni++) {
                        int n = colbase + ni * 16 + l15;
                        short8 bh = ld8(Whh0hi + (size_t)n * HSZ + kc * 32 + quad * 8);
                        short8 bl = ld8(Whh0lo + (size_t)n * HSZ + kc * 32 + quad * 8);
                        accA[ni] = MFMA(ah, bh, accA[ni]);
                        accB[ni] = MFMA(al, bh, accB[ni]);
                        accB[ni] = MFMA(ah, bl, accB[ni]);
                    }
                }
#pragma unroll
                for (int ni = 0; ni < 4; ni++) {
                    int col = colbase + ni * 16 + l15;
                    float bias = bih0[col] + bhh0[col];
#pragma unroll
                    for (int r = 0; r < 4; r++) {
                        int row = mb + quad * 4 + r;
                        float vv = tanhf(accA[ni][r] + accB[ni][r] + bias);
                        bf16 hb = __float2bfloat16(vv);
                        st2_sc(hc_hi + (size_t)row * HSZ + col, hb);
                        st2_sc(hc_lo + (size_t)row * HSZ + col,
                               __float2bfloat16(vv - b2f(hb)));
                    }
                }
            }
        } else if (bid < NB0 + NB1) {
            // ---- layer1: 16 rows x 128 cols ----
            const int t = p - 1;
            if (t >= 0 && t < TLEN) {
                const int fb = bid - NB0;
                const int rs = t & 1, wsl = rs ^ 1;
                const int mb = (fb >> 2) * 16;
                const int colbase = (fb & 3) * 128 + wv * 32;
                const bf16* s0 = h0hi + (size_t)wsl * (BSZ * HSZ) + (size_t)mb * HSZ; // h0_t
                const bf16* s1 = h0lo + (size_t)wsl * (BSZ * HSZ) + (size_t)mb * HSZ;
                const bf16* s2 = h1hi + (size_t)rs  * (BSZ * HSZ) + (size_t)mb * HSZ; // h1_{t-1}
                const bf16* s3 = h1lo + (size_t)rs  * (BSZ * HSZ) + (size_t)mb * HSZ;
                bf16* hc_hi = h1hi + (size_t)wsl * (BSZ * HSZ);
                bf16* hc_lo = h1lo + (size_t)wsl * (BSZ * HSZ);

                short8 v[16];
                ld8sc(s0 + goff, s0 + goff + 128, s0 + goff + 256, s0 + goff + 384,
                      s1 + goff, s1 + goff + 128, s1 + goff + 256, s1 + goff + 384, v);
                ld8sc(s2 + goff, s2 + goff + 128, s2 + goff + 256, s2 + goff + 384,
                      s3 + goff, s3 + goff + 128, s3 + goff + 256, s3 + goff + 384, v + 8);
#pragma unroll
                for (int i = 0; i < 4; i++) {
                    *(short8*)(smem + 0 * 16384 + tid * 16 + i * 4096) = v[i];
                    *(short8*)(smem + 1 * 16384 + tid * 16 + i * 4096) = v[4 + i];
                    *(short8*)(smem + 2 * 16384 + tid * 16 + i * 4096) = v[8 + i];
                    *(short8*)(smem + 3 * 16384 + tid * 16 + i * 4096) = v[12 + i];
                }
                __syncthreads();

                f32x4 accA[2] = {}, accB[2] = {};
                for (int kc = 0; kc < 16; kc++) {
                    const int coff = (kc * 64 + lane) * 16;
                    short8 p0 = *(const short8*)(smem + 0 * 16384 + coff);
                    short8 q0 = *(const short8*)(smem + 1 * 16384 + coff);
                    short8 r0 = *(const short8*)(smem + 2 * 16384 + coff);
                    short8 s0f = *(const short8*)(smem + 3 * 16384 + coff);
#pragma unroll
                    for (int ni = 0; ni < 2; ni++) {
                        int n = colbase + ni * 16 + l15;
                        short8 bih = ld8(Wih1hi + (size_t)n * HSZ + kc * 32 + quad * 8);
                        short8 bil = ld8(Wih1lo + (size_t)n * HSZ + kc * 32 + quad * 8);
                        short8 bhh = ld8(Whh1hi + (size_t)n * HSZ + kc * 32 + quad * 8);
                        short8 bhl = ld8(Whh1lo + (size_t)n * HSZ + kc * 32 + quad * 8);
                        accA[ni] = MFMA(p0, bih, accA[ni]);
                        accB[ni] = MFMA(q0, bih, accB[ni]);
                        accB[ni] = MFMA(p0, bil, accB[ni]);
                        accA[ni] = MFMA(r0, bhh, accA[ni]);
                        accB[ni] = MFMA(s0f, bhh, accB[ni]);
                        accB[ni] = MFMA(r0, bhl, accB[ni]);
                    }
                }
#pragma unroll
                for (int ni = 0; ni < 2; ni++) {
                    int col = colbase + ni * 16 + l15;
                    float bias = bih1[col] + bhh1[col];
#pragma unroll
                    for (int r = 0; r < 4; r++) {
                        int row = mb + quad * 4 + r;
                        float vv = tanhf(accA[ni][r] + accB[ni][r] + bias);
                        bf16 hb = __float2bfloat16(vv);
                        st2_sc(hc_hi + (size_t)row * HSZ + col, hb);
                        st2_sc(hc_lo + (size_t)row * HSZ + col,
                               __float2bfloat16(vv - b2f(hb)));
                    }
                }
            }
        } else {
            // ---- FC: 32 rows x 128 cols ----
            const int tout = p - 2;
            if (tout >= 0) {
                const int fb = bid - NB0 - NB1;
                const int slot = (tout & 1) ^ 1;
                const int mb = fb * 32;
                const int colbase = wv * 32;
                const bf16* hh = h1hi + (size_t)slot * (BSZ * HSZ);
                const bf16* hl = h1lo + (size_t)slot * (BSZ * HSZ);
                const bf16* s0 = hh + (size_t)mb * HSZ;          // hi rows 0-15
                const bf16* s1 = hh + (size_t)(mb + 16) * HSZ;   // hi rows 16-31
                const bf16* s2 = hl + (size_t)mb * HSZ;          // lo rows 0-15
                const bf16* s3 = hl + (size_t)(mb + 16) * HSZ;   // lo rows 16-31

                short8 v[16];
                ld8sc(s0 + goff, s0 + goff + 128, s0 + goff + 256, s0 + goff + 384,
                      s1 + goff, s1 + goff + 128, s1 + goff + 256, s1 + goff + 384, v);
                ld8sc(s2 + goff, s2 + goff + 128, s2 + goff + 256, s2 + goff + 384,
                      s3 + goff, s3 + goff + 128, s3 + goff + 256, s3 + goff + 384, v + 8);
#pragma unroll
                for (int i = 0; i < 4; i++) {
                    *(short8*)(smem + 0 * 16384 + tid * 16 + i * 4096) = v[i];
                    *(short8*)(smem + 1 * 16384 + tid * 16 + i * 4096) = v[4 + i];
                    *(short8*)(smem + 2 * 16384 + tid * 16 + i * 4096) = v[8 + i];
                    *(short8*)(smem + 3 * 16384 + tid * 16 + i * 4096) = v[12 + i];
                }
                __syncthreads();

                f32x4 accA[2][2] = {}, accB[2][2] = {};
                for (int kc = 0; kc < 16; kc++) {
                    const int coff = (kc * 64 + lane) * 16;
                    short8 ah0 = *(const short8*)(smem + 0 * 16384 + coff);
                    short8 ah1 = *(const short8*)(smem + 1 * 16384 + coff);
                    short8 al0 = *(const short8*)(smem + 2 * 16384 + coff);
                    short8 al1 = *(const short8*)(smem + 3 * 16384 + coff);
#pragma unroll
                    for (int ni = 0; ni < 2; ni++) {
                        int n = colbase + ni * 16 + l15;
                        short8 bh = ld8(Wfchi + (size_t)n * HSZ + kc * 32 + quad * 8);
                        short8 bl = ld8(Wfclo + (size_t)n * HSZ + kc * 32 + quad * 8);
                        accA[0][ni] = MFMA(ah0, bh, accA[0][ni]);
                        accB[0][ni] = MFMA(al0, bh, accB[0][ni]);
                        accB[0][ni] = MFMA(ah0, bl, accB[0][ni]);
                        accA[1][ni] = MFMA(ah1, bh, accA[1][ni]);
                        accB[1][ni] = MFMA(al1, bh, accB[1][ni]);
                        accB[1][ni] = MFMA(ah1, bl, accB[1][ni]);
                    }
                }
#pragma unroll
                for (int mi = 0; mi < 2; mi++) {
#pragma unroll
                    for (int ni = 0; ni < 2; ni++) {
                        int col = colbase + ni * 16 + l15;
                        float bias = bfc[col];
#pragma unroll
                        for (int r = 0; r < 4; r++) {
                            int row = mb + mi * 16 + quad * 4 + r;
                            out[((size_t)row * TLEN + tout) * VSZ + col] =
                                accA[mi][ni][r] + accB[mi][ni][r] + bias;
                        }
                    }
                }
            }
        }
        if (p < TLEN + 1)
            grid_barrier(flags, bid, p);
    }
}

extern "C" void kernel_launch(void* const* d_in, const int* in_sizes, int n_in,
                              void* d_out, int out_size, void* d_ws, size_t ws_size,
                              hipStream_t stream) {
    const int*   x    = (const int*)d_in[0];
    const float* emb  = (const float*)d_in[1];
    const float* Wih0 = (const float*)d_in[2];
    const float* bih0 = (const float*)d_in[3];
    const float* Whh0 = (const float*)d_in[4];
    const float* bhh0 = (const float*)d_in[5];
    const float* Wih1 = (const float*)d_in[6];
    const float* bih1 = (const float*)d_in[7];
    const float* Whh1 = (const float*)d_in[8];
    const float* bhh1 = (const float*)d_in[9];
    const float* Wfc  = (const float*)d_in[10];
    const float* bfc  = (const float*)d_in[11];
    float* out = (float*)d_out;
    bf16* ws   = (bf16*)d_ws;

    const int total = 3 * HSZ * HSZ + HSZ * EMBD + VSZ * HSZ + VSZ * EMBD
                    + (8 * BSZ * HSZ) / 2 + 128 * 32;
    k_prep<<<(total + 255) / 256, 256, 0, stream>>>(emb, Wih0, Whh0, Wih1, Whh1, Wfc, ws);

    k_persist<<<NBLK, 256, 65536, stream>>>(x, bih0, bhh0, bih1, bhh1, bfc, ws, out);
}

// Round 6
// 11142.348 us; speedup vs baseline: 2.5125x; 1.0188x over previous
//
#include <hip/hip_runtime.h>
#include <hip/hip_bf16.h>

#define VSZ 128
#define EMBD 64
#define HSZ 512
#define BSZ 256
#define TLEN 512
#define NB0 32            // layer0 blocks: 16 rows x 256 cols
#define NB1 64            // layer1 blocks: 16 rows x 128 cols
#define NBFC 8            // fc blocks:     32 rows x 128 cols
#define NBLK (NB0 + NB1 + NBFC)   // 104

typedef __attribute__((ext_vector_type(8))) short short8;
typedef __attribute__((ext_vector_type(4))) float f32x4;
typedef __hip_bfloat16 bf16;

#define SQ   ((size_t)HSZ*HSZ)
#define SLAB ((size_t)BSZ*HSZ)    // one h slab (131072 elems)

// ---- workspace layout (bf16 element offsets) ----
#define O_WHH0HI ((size_t)0)
#define O_WHH0LO (O_WHH0HI + SQ)
#define O_WIH1HI (O_WHH0LO + SQ)
#define O_WIH1LO (O_WIH1HI + SQ)
#define O_WHH1HI (O_WIH1LO + SQ)
#define O_WHH1LO (O_WHH1HI + SQ)
#define O_WIH0HI (O_WHH1LO + SQ)          // [N=512][K=64]
#define O_WIH0LO (O_WIH0HI + (size_t)HSZ*EMBD)
#define O_WFCHI  (O_WIH0LO + (size_t)HSZ*EMBD)   // [N=128][K=512]
#define O_WFCLO  (O_WFCHI + (size_t)VSZ*HSZ)
#define O_EMBHI  (O_WFCLO + (size_t)VSZ*HSZ)     // [128][64] row-major
#define O_EMBLO  (O_EMBHI + (size_t)VSZ*EMBD)
#define O_H0HI   (O_EMBLO + (size_t)VSZ*EMBD)    // [4][256][512] depth-4 ring
#define O_H0LO   (O_H0HI + 4*SLAB)
#define O_H1HI   (O_H0LO + 4*SLAB)
#define O_H1LO   (O_H1HI + 4*SLAB)
#define O_CNT    (O_H1LO + 4*SLAB)               // 128 slots x 32 ints (128B pad)

static __device__ __forceinline__ short8 ld8(const bf16* p) {
    return *(const short8*)p;
}
static __device__ __forceinline__ float b2f(bf16 v) { return __bfloat162float(v); }

#define MFMA(a,b,c) __builtin_amdgcn_mfma_f32_16x16x32_bf16((a),(b),(c),0,0,0)

// ---- coherent (cache-bypass) primitives: the ONLY cross-XCD traffic ----
static __device__ __forceinline__ void ld8sc(
    const bf16* p0, const bf16* p1, const bf16* p2, const bf16* p3,
    const bf16* p4, const bf16* p5, const bf16* p6, const bf16* p7, short8* o)
{
    asm volatile(
        "global_load_dwordx4 %0, %8, off sc0 sc1\n\t"
        "global_load_dwordx4 %1, %9, off sc0 sc1\n\t"
        "global_load_dwordx4 %2, %10, off sc0 sc1\n\t"
        "global_load_dwordx4 %3, %11, off sc0 sc1\n\t"
        "global_load_dwordx4 %4, %12, off sc0 sc1\n\t"
        "global_load_dwordx4 %5, %13, off sc0 sc1\n\t"
        "global_load_dwordx4 %6, %14, off sc0 sc1\n\t"
        "global_load_dwordx4 %7, %15, off sc0 sc1\n\t"
        "s_waitcnt vmcnt(0)"
        : "=&v"(o[0]), "=&v"(o[1]), "=&v"(o[2]), "=&v"(o[3]),
          "=&v"(o[4]), "=&v"(o[5]), "=&v"(o[6]), "=&v"(o[7])
        : "v"(p0), "v"(p1), "v"(p2), "v"(p3), "v"(p4), "v"(p5), "v"(p6), "v"(p7)
        : "memory");
}

static __device__ __forceinline__ void st2_sc(bf16* p, bf16 v) {
    unsigned short us;
    __builtin_memcpy(&us, &v, 2);
    unsigned u = us;
    asm volatile("global_store_short %0, %1, off sc0 sc1" :: "v"(p), "v"(u) : "memory");
}

// ---- one prep kernel: split/transpose weights + zero ring slot 3 + counters ----
__global__ void k_prep(const float* __restrict__ emb, const float* __restrict__ Wih0,
                       const float* __restrict__ Whh0, const float* __restrict__ Wih1,
                       const float* __restrict__ Whh1, const float* __restrict__ Wfc,
                       bf16* __restrict__ ws) {
    int j = blockIdx.x * blockDim.x + threadIdx.x;
    const int SQi = HSZ * HSZ;
    if (j < SQi) {          // Whh0T
        int n = j / HSZ, k = j - n * HSZ;
        float w = Whh0[k * HSZ + n];
        bf16 hi = __float2bfloat16(w);
        ws[O_WHH0HI + j] = hi; ws[O_WHH0LO + j] = __float2bfloat16(w - b2f(hi));
        return;
    }
    j -= SQi;
    if (j < SQi) {          // Wih1T
        int n = j / HSZ, k = j - n * HSZ;
        float w = Wih1[k * HSZ + n];
        bf16 hi = __float2bfloat16(w);
        ws[O_WIH1HI + j] = hi; ws[O_WIH1LO + j] = __float2bfloat16(w - b2f(hi));
        return;
    }
    j -= SQi;
    if (j < SQi) {          // Whh1T
        int n = j / HSZ, k = j - n * HSZ;
        float w = Whh1[k * HSZ + n];
        bf16 hi = __float2bfloat16(w);
        ws[O_WHH1HI + j] = hi; ws[O_WHH1LO + j] = __float2bfloat16(w - b2f(hi));
        return;
    }
    j -= SQi;
    if (j < HSZ * EMBD) {  // Wih0T: out [512][64], in [64][512]
        int n = j / EMBD, k = j - n * EMBD;
        float w = Wih0[k * HSZ + n];
        bf16 hi = __float2bfloat16(w);
        ws[O_WIH0HI + j] = hi; ws[O_WIH0LO + j] = __float2bfloat16(w - b2f(hi));
        return;
    }
    j -= HSZ * EMBD;
    if (j < VSZ * HSZ) {   // WfcT: out [128][512], in [512][128]
        int n = j / HSZ, k = j - n * HSZ;
        float w = Wfc[k * VSZ + n];
        bf16 hi = __float2bfloat16(w);
        ws[O_WFCHI + j] = hi; ws[O_WFCLO + j] = __float2bfloat16(w - b2f(hi));
        return;
    }
    j -= VSZ * HSZ;
    if (j < VSZ * EMBD) {  // emb split
        float w = emb[j];
        bf16 hi = __float2bfloat16(w);
        ws[O_EMBHI + j] = hi; ws[O_EMBLO + j] = __float2bfloat16(w - b2f(hi));
        return;
    }
    j -= VSZ * EMBD;
    const int NZ = (int)(4 * SLAB / 2);   // zero slot-3 of the 4 h rings (as u32)
    if (j < NZ) {
        int k = j / (int)(SLAB / 2);      // which ring (h0hi,h0lo,h1hi,h1lo)
        int off = j - k * (int)(SLAB / 2);
        ((unsigned int*)(ws + O_H0HI + (size_t)(4 * k + 3) * SLAB))[off] = 0u;
        return;
    }
    j -= NZ;
    if (j < 128 * 32) {    // counters = 0
        ((int*)(ws + O_CNT))[j] = 0;
    }
}

// ---- persistent dataflow kernel: no global barrier, per-block step counters ----
__global__ __launch_bounds__(256) void k_persist(
    const int* __restrict__ x,
    const float* __restrict__ bih0, const float* __restrict__ bhh0,
    const float* __restrict__ bih1, const float* __restrict__ bhh1,
    const float* __restrict__ bfc,
    bf16* __restrict__ ws, float* __restrict__ out)
{
    extern __shared__ char smem[];
    const int tid  = (int)threadIdx.x;
    const int lane = tid & 63;
    const int wv   = tid >> 6;
    const int l15  = lane & 15;
    const int quad = lane >> 4;
    const int bid  = (int)blockIdx.x;

    int* cnt = (int*)(ws + O_CNT);
    const bf16* embhi  = ws + O_EMBHI;  const bf16* emblo  = ws + O_EMBLO;
    const bf16* Wih0hi = ws + O_WIH0HI; const bf16* Wih0lo = ws + O_WIH0LO;
    const bf16* Whh0hi = ws + O_WHH0HI; const bf16* Whh0lo = ws + O_WHH0LO;
    const bf16* Wih1hi = ws + O_WIH1HI; const bf16* Wih1lo = ws + O_WIH1LO;
    const bf16* Whh1hi = ws + O_WHH1HI; const bf16* Whh1lo = ws + O_WHH1LO;
    const bf16* Wfchi  = ws + O_WFCHI;  const bf16* Wfclo  = ws + O_WFCLO;
    bf16* h0hi = ws + O_H0HI; bf16* h0lo = ws + O_H0LO;
    bf16* h1hi = ws + O_H1HI; bf16* h1lo = ws + O_H1LO;

    // staging addr: global elem offset within a 16-row slab
    const size_t goff = (size_t)l15 * HSZ + (tid >> 6) * 32 + quad * 8;

    // ---- per-lane dependency table (slot index into cnt, need = t + delta) ----
    int dslot = -1, ddelta = 0;
    if (bid < NB0) {
        int rg = bid >> 1;
        if (lane == 0)              { dslot = bid ^ 1;                ddelta = 0; }
        else if (lane <= 4)         { dslot = 32 + 4 * rg + (lane-1); ddelta = -3; }
    } else if (bid < NB0 + NB1) {
        int lb = bid - NB0, rg = lb >> 2, q = lb & 3;
        if (lane == 0)              { dslot = 2 * rg;                 ddelta = 1; }
        else if (lane == 1)         { dslot = 2 * rg + 1;             ddelta = 1; }
        else if (lane <= 4) {
            int k = lane - 2;                       // 0..2 -> non-self siblings
            int qq = k + (k >= q ? 1 : 0);
            dslot = 32 + 4 * rg + qq;               ddelta = 0;
        }
        else if (lane == 5)         { dslot = 96 + (rg >> 1);         ddelta = -3; }
    } else {
        int f = bid - NB0 - NB1;
        if (lane < 8)               { dslot = 32 + 8 * f + lane;      ddelta = 1; }
    }
    const int* dp = (dslot >= 0) ? (cnt + (size_t)dslot * 32) : (const int*)0;
    int* myc = cnt + (size_t)bid * 32;

    for (int t = 0; t < TLEN; ++t) {
        // ---- poll producers (wave 0 only, 1 word per dependency) ----
        if (wv == 0) {
            const int need = t + ddelta;
            for (;;) {
                int ok = 1;
                if (dp) {
                    int v;
                    asm volatile("global_load_dword %0, %1, off sc0 sc1\n\t"
                                 "s_waitcnt vmcnt(0)"
                                 : "=v"(v) : "v"(dp) : "memory");
                    ok = (v >= need);
                }
                if (__all(ok)) break;
                __builtin_amdgcn_s_sleep(1);
            }
        }
        __syncthreads();

        const int wsl = t & 3;          // slot being written this step
        const int rsl = (t - 1) & 3;    // previous-step slot

        if (bid < NB0) {
            // ---- layer0: h0[t] = tanh(emb[x]@Wih0 + h0[t-1]@Whh0 + b) ----
            const int mb = (bid >> 1) * 16;
            const int colbase = (bid & 1) * 256 + wv * 64;
            const bf16* sp0 = h0hi + (size_t)rsl * SLAB + (size_t)mb * HSZ;
            const bf16* sp1 = h0lo + (size_t)rsl * SLAB + (size_t)mb * HSZ;
            bf16* hc_hi = h0hi + (size_t)wsl * SLAB;
            bf16* hc_lo = h0lo + (size_t)wsl * SLAB;

            short8 v[8];
            ld8sc(sp0 + goff, sp0 + goff + 128, sp0 + goff + 256, sp0 + goff + 384,
                  sp1 + goff, sp1 + goff + 128, sp1 + goff + 256, sp1 + goff + 384, v);
#pragma unroll
            for (int i = 0; i < 4; i++) {
                *(short8*)(smem + 0 * 16384 + tid * 16 + i * 4096) = v[i];
                *(short8*)(smem + 1 * 16384 + tid * 16 + i * 4096) = v[4 + i];
            }
            __syncthreads();

            const int xr = x[(mb + l15) * TLEN + t];
            f32x4 accA[4] = {}, accB[4] = {};
#pragma unroll
            for (int kc2 = 0; kc2 < 2; kc2++) {
                short8 eh = ld8(embhi + (size_t)xr * EMBD + kc2 * 32 + quad * 8);
                short8 el = ld8(emblo + (size_t)xr * EMBD + kc2 * 32 + quad * 8);
#pragma unroll
                for (int ni = 0; ni < 4; ni++) {
                    int n = colbase + ni * 16 + l15;
                    short8 bh = ld8(Wih0hi + (size_t)n * EMBD + kc2 * 32 + quad * 8);
                    short8 bl = ld8(Wih0lo + (size_t)n * EMBD + kc2 * 32 + quad * 8);
                    accA[ni] = MFMA(eh, bh, accA[ni]);
                    accB[ni] = MFMA(el, bh, accB[ni]);
                    accB[ni] = MFMA(eh, bl, accB[ni]);
                }
            }
            for (int kc = 0; kc < 16; kc++) {
                const int coff = (kc * 64 + lane) * 16;
                short8 ah = *(const short8*)(smem + 0 * 16384 + coff);
                short8 al = *(const short8*)(smem + 1 * 16384 + coff);
#pragma unroll
                for (int ni = 0; ni < 4; ni++) {
                    int n = colbase + ni * 16 + l15;
                    short8 bh = ld8(Whh0hi + (size_t)n * HSZ + kc * 32 + quad * 8);
                    short8 bl = ld8(Whh0lo + (size_t)n * HSZ + kc * 32 + quad * 8);
                    accA[ni] = MFMA(ah, bh, accA[ni]);
                    accB[ni] = MFMA(al, bh, accB[ni]);
                    accB[ni] = MFMA(ah, bl, accB[ni]);
                }
            }
#pragma unroll
            for (int ni = 0; ni < 4; ni++) {
                int col = colbase + ni * 16 + l15;
                float bias = bih0[col] + bhh0[col];
#pragma unroll
                for (int r = 0; r < 4; r++) {
                    int row = mb + quad * 4 + r;
                    float vv = tanhf(accA[ni][r] + accB[ni][r] + bias);
                    bf16 hb = __float2bfloat16(vv);
                    st2_sc(hc_hi + (size_t)row * HSZ + col, hb);
                    st2_sc(hc_lo + (size_t)row * HSZ + col,
                           __float2bfloat16(vv - b2f(hb)));
                }
            }
        } else if (bid < NB0 + NB1) {
            // ---- layer1: h1[t] = tanh(h0[t]@Wih1 + h1[t-1]@Whh1 + b) ----
            const int fb = bid - NB0;
            const int mb = (fb >> 2) * 16;
            const int colbase = (fb & 3) * 128 + wv * 32;
            const bf16* s0 = h0hi + (size_t)wsl * SLAB + (size_t)mb * HSZ;  // h0[t]
            const bf16* s1 = h0lo + (size_t)wsl * SLAB + (size_t)mb * HSZ;
            const bf16* s2 = h1hi + (size_t)rsl * SLAB + (size_t)mb * HSZ;  // h1[t-1]
            const bf16* s3 = h1lo + (size_t)rsl * SLAB + (size_t)mb * HSZ;
            bf16* hc_hi = h1hi + (size_t)wsl * SLAB;
            bf16* hc_lo = h1lo + (size_t)wsl * SLAB;

            short8 v[16];
            ld8sc(s0 + goff, s0 + goff + 128, s0 + goff + 256, s0 + goff + 384,
                  s1 + goff, s1 + goff + 128, s1 + goff + 256, s1 + goff + 384, v);
            ld8sc(s2 + goff, s2 + goff + 128, s2 + goff + 256, s2 + goff + 384,
                  s3 + goff, s3 + goff + 128, s3 + goff + 256, s3 + goff + 384, v + 8);
#pragma unroll
            for (int i = 0; i < 4; i++) {
                *(short8*)(smem + 0 * 16384 + tid * 16 + i * 4096) = v[i];
                *(short8*)(smem + 1 * 16384 + tid * 16 + i * 4096) = v[4 + i];
                *(short8*)(smem + 2 * 16384 + tid * 16 + i * 4096) = v[8 + i];
                *(short8*)(smem + 3 * 16384 + tid * 16 + i * 4096) = v[12 + i];
            }
            __syncthreads();

            f32x4 accA[2] = {}, accB[2] = {};
            for (int kc = 0; kc < 16; kc++) {
                const int coff = (kc * 64 + lane) * 16;
                short8 p0 = *(const short8*)(smem + 0 * 16384 + coff);
                short8 q0 = *(const short8*)(smem + 1 * 16384 + coff);
                short8 r0 = *(const short8*)(smem + 2 * 16384 + coff);
                short8 s0f = *(const short8*)(smem + 3 * 16384 + coff);
#pragma unroll
                for (int ni = 0; ni < 2; ni++) {
                    int n = colbase + ni * 16 + l15;
                    short8 bih = ld8(Wih1hi + (size_t)n * HSZ + kc * 32 + quad * 8);
                    short8 bil = ld8(Wih1lo + (size_t)n * HSZ + kc * 32 + quad * 8);
                    short8 bhh = ld8(Whh1hi + (size_t)n * HSZ + kc * 32 + quad * 8);
                    short8 bhl = ld8(Whh1lo + (size_t)n * HSZ + kc * 32 + quad * 8);
                    accA[ni] = MFMA(p0, bih, accA[ni]);
                    accB[ni] = MFMA(q0, bih, accB[ni]);
                    accB[ni] = MFMA(p0, bil, accB[ni]);
                    accA[ni] = MFMA(r0, bhh, accA[ni]);
                    accB[ni] = MFMA(s0f, bhh, accB[ni]);
                    accB[ni] = MFMA(r0, bhl, accB[ni]);
                }
            }
#pragma unroll
            for (int ni = 0; ni < 2; ni++) {
                int col = colbase + ni * 16 + l15;
                float bias = bih1[col] + bhh1[col];
#pragma unroll
                for (int r = 0; r < 4; r++) {
                    int row = mb + quad * 4 + r;
                    float vv = tanhf(accA[ni][r] + accB[ni][r] + bias);
                    bf16 hb = __float2bfloat16(vv);
                    st2_sc(hc_hi + (size_t)row * HSZ + col, hb);
                    st2_sc(hc_lo + (size_t)row * HSZ + col,
                           __float2bfloat16(vv - b2f(hb)));
                }
            }
        } else {
            // ---- FC: logits[:, t, :] = h1[t] @ Wfc + b_fc ----
            const int f = bid - NB0 - NB1;
            const int mb = f * 32;
            const int colbase = wv * 32;
            const bf16* hh = h1hi + (size_t)wsl * SLAB;
            const bf16* hl = h1lo + (size_t)wsl * SLAB;
            const bf16* s0 = hh + (size_t)mb * HSZ;
            const bf16* s1 = hh + (size_t)(mb + 16) * HSZ;
            const bf16* s2 = hl + (size_t)mb * HSZ;
            const bf16* s3 = hl + (size_t)(mb + 16) * HSZ;

            short8 v[16];
            ld8sc(s0 + goff, s0 + goff + 128, s0 + goff + 256, s0 + goff + 384,
                  s1 + goff, s1 + goff + 128, s1 + goff + 256, s1 + goff + 384, v);
            ld8sc(s2 + goff, s2 + goff + 128, s2 + goff + 256, s2 + goff + 384,
                  s3 + goff, s3 + goff + 128, s3 + goff + 256, s3 + goff + 384, v + 8);
#pragma unroll
            for (int i = 0; i < 4; i++) {
                *(short8*)(smem + 0 * 16384 + tid * 16 + i * 4096) = v[i];
                *(short8*)(smem + 1 * 16384 + tid * 16 + i * 4096) = v[4 + i];
                *(short8*)(smem + 2 * 16384 + tid * 16 + i * 4096) = v[8 + i];
                *(short8*)(smem + 3 * 16384 + tid * 16 + i * 4096) = v[12 + i];
            }
            __syncthreads();

            f32x4 accA[2][2] = {}, accB[2][2] = {};
            for (int kc = 0; kc < 16; kc++) {
                const int coff = (kc * 64 + lane) * 16;
                short8 ah0 = *(const short8*)(smem + 0 * 16384 + coff);
                short8 ah1 = *(const short8*)(smem + 1 * 16384 + coff);
                short8 al0 = *(const short8*)(smem + 2 * 16384 + coff);
                short8 al1 = *(const short8*)(smem + 3 * 16384 + coff);
#pragma unroll
                for (int ni = 0; ni < 2; ni++) {
                    int n = colbase + ni * 16 + l15;
                    short8 bh = ld8(Wfchi + (size_t)n * HSZ + kc * 32 + quad * 8);
                    short8 bl = ld8(Wfclo + (size_t)n * HSZ + kc * 32 + quad * 8);
                    accA[0][ni] = MFMA(ah0, bh, accA[0][ni]);
                    accB[0][ni] = MFMA(al0, bh, accB[0][ni]);
                    accB[0][ni] = MFMA(ah0, bl, accB[0][ni]);
                    accA[1][ni] = MFMA(ah1, bh, accA[1][ni]);
                    accB[1][ni] = MFMA(al1, bh, accB[1][ni]);
                    accB[1][ni] = MFMA(ah1, bl, accB[1][ni]);
                }
            }
#pragma unroll
            for (int mi = 0; mi < 2; mi++) {
#pragma unroll
                for (int ni = 0; ni < 2; ni++) {
                    int col = colbase + ni * 16 + l15;
                    float bias = bfc[col];
#pragma unroll
                    for (int r = 0; r < 4; r++) {
                        int row = mb + mi * 16 + quad * 4 + r;
                        out[((size_t)row * TLEN + t) * VSZ + col] =
                            accA[mi][ni][r] + accB[mi][ni][r] + bias;
                    }
                }
            }
        }

        // ---- publish completion: drain stores, bump own counter ----
        asm volatile("s_waitcnt vmcnt(0)" ::: "memory");
        __syncthreads();
        if (tid == 0) {
            int val = t + 1;
            asm volatile("global_store_dword %0, %1, off sc0 sc1"
                         :: "v"(myc), "v"(val) : "memory");
        }
    }
}

extern "C" void kernel_launch(void* const* d_in, const int* in_sizes, int n_in,
                              void* d_out, int out_size, void* d_ws, size_t ws_size,
                              hipStream_t stream) {
    const int*   x    = (const int*)d_in[0];
    const float* emb  = (const float*)d_in[1];
    const float* Wih0 = (const float*)d_in[2];
    const float* bih0 = (const float*)d_in[3];
    const float* Whh0 = (const float*)d_in[4];
    const float* bhh0 = (const float*)d_in[5];
    const float* Wih1 = (const float*)d_in[6];
    const float* bih1 = (const float*)d_in[7];
    const float* Whh1 = (const float*)d_in[8];
    const float* bhh1 = (const float*)d_in[9];
    const float* Wfc  = (const float*)d_in[10];
    const float* bfc  = (const float*)d_in[11];
    float* out = (float*)d_out;
    bf16* ws   = (bf16*)d_ws;

    const int total = 3 * HSZ * HSZ + HSZ * EMBD + VSZ * HSZ + VSZ * EMBD
                    + (int)(4 * SLAB / 2) + 128 * 32;
    k_prep<<<(total + 255) / 256, 256, 0, stream>>>(emb, Wih0, Whh0, Wih1, Whh1, Wfc, ws);

    k_persist<<<NBLK, 256, 65536, stream>>>(x, bih0, bhh0, bih1, bhh1, bfc, ws, out);
}